// Round 16
// baseline (286.751 us; speedup 1.0000x reference)
//
#include <hip/hip_runtime.h>
#include <math.h>

#define BB 64
#define NN 197
#define HH 10
#define DD 64
#define CC 640
#define C3 1920
#define LR 64
#define MTOT (BB*NN)          // 12608
#define SCALE 0.125f

typedef unsigned short u16;
typedef __bf16 bf16x8 __attribute__((ext_vector_type(8)));
typedef float f32x4 __attribute__((ext_vector_type(4)));

__device__ __forceinline__ void split_bf16(float f, u16& hi, u16& lo) {
  unsigned u = __float_as_uint(f);
  unsigned r = u + 0x7FFF + ((u >> 16) & 1);
  u16 hb = (u16)(r >> 16);
  float fh = __uint_as_float((unsigned)hb << 16);
  float dl = f - fh;
  unsigned u2 = __float_as_uint(dl);
  unsigned r2 = u2 + 0x7FFF + ((u2 >> 16) & 1);
  hi = hb; lo = (u16)(r2 >> 16);
}

__device__ __forceinline__ u16 bf16rn(float f) {
  unsigned u = __float_as_uint(f);
  return (u16)((u + 0x7FFF + ((u >> 16) & 1)) >> 16);
}
__device__ __forceinline__ float bf16tof(u16 v) {
  return __uint_as_float((unsigned)v << 16);
}

// ---------------------------------------------------------------------------
// K1: w_eff = perm3(w_qkv + (lora_a @ lora_b)^T) -> bf16 hi/lo split
// ---------------------------------------------------------------------------
__global__ __launch_bounds__(256) void k_weff(
    const float* __restrict__ w_qkv, const float* __restrict__ la,
    const float* __restrict__ lb, u16* __restrict__ whi, u16* __restrict__ wlo) {
  int idx = blockIdx.x * 256 + threadIdx.x;      // covers 1920*640
  int i = idx / CC, j = idx % CC;
  int src = 3 * (i % CC) + (i / CC);
  float acc = w_qkv[(size_t)src * CC + j];
  const float* laj = la + (size_t)j * LR;
  const float* lbs = lb + src;
  #pragma unroll 8
  for (int r = 0; r < LR; ++r) acc = fmaf(laj[r], lbs[(size_t)r * C3], acc);
  u16 h, l; split_bf16(acc, h, l);
  whi[idx] = h; wlo[idx] = l;
}

// fp32 -> bf16 hi/lo split
__global__ __launch_bounds__(256) void k_cvt(
    const float* __restrict__ in, u16* __restrict__ hi, u16* __restrict__ lo, int n4) {
  int i = blockIdx.x * 256 + threadIdx.x;
  if (i >= n4) return;
  float4 v = ((const float4*)in)[i];
  float f[4] = {v.x, v.y, v.z, v.w};
  ushort4 H, L;
  u16 hh, ll;
  split_bf16(f[0], hh, ll); H.x = hh; L.x = ll;
  split_bf16(f[1], hh, ll); H.y = hh; L.y = ll;
  split_bf16(f[2], hh, ll); H.z = hh; L.z = ll;
  split_bf16(f[3], hh, ll); H.w = hh; L.w = ll;
  ((ushort4*)hi)[i] = H;
  ((ushort4*)lo)[i] = L;
}

__device__ __forceinline__ int perm640(int i) {
  return (i < 214) ? 3 * i : (i < 427 ? 3 * (i - 214) + 1 : 3 * (i - 427) + 2);
}

__global__ __launch_bounds__(256) void k_cvtw(
    const float* __restrict__ wp, u16* __restrict__ hi, u16* __restrict__ lo) {
  int idx = blockIdx.x * 256 + threadIdx.x;      // covers 640*640
  int i = idx / CC, j = idx % CC;
  float v = wp[(size_t)perm640(i) * CC + j];
  u16 h, l; split_bf16(v, h, l);
  hi[idx] = h; lo[idx] = l;
}

// ---------------------------------------------------------------------------
// k_prep: (a) tabK -> bf16 hi/lo. (b) gM bucket one-hot [32t][224k] pre-
// swizzle-linearized for V-tile. (c) gMT transposed one-hot [224k][32t],
// pre-swizzle-linearized (byte ^= ((row>>1)&3)<<4).
// ---------------------------------------------------------------------------
__global__ __launch_bounds__(256) void k_prep(
    const float* __restrict__ tkv, const float* __restrict__ tkh,
    u16* __restrict__ thi, u16* __restrict__ tlo, u16* __restrict__ gM,
    u16* __restrict__ gMT) {
  for (int idx = threadIdx.x; idx < 4096; idx += 256) {
    int row = idx >> 6, d = idx & 63;
    float v = row < 30 ? tkv[row * 64 + d] : (row < 60 ? tkh[(row - 30) * 64 + d] : 0.f);
    u16 hh, ll; split_bf16(v, hh, ll);
    thi[idx] = hh; tlo[idx] = ll;
  }
  for (int j = threadIdx.x; j < 7168; j += 256) {
    int b = 2 * j;
    u16 v = 0;
    int r0 = b / 448;
    for (int dr = -1; dr <= 1; ++dr) {
      int row = r0 + dr;
      if (row < 0 || row >= 32) continue;
      int g = (row & 7) ^ ((row >> 3) & 7);
      int off = (b ^ (g << 4)) - row * 448;
      if (off >= 0 && off < 448) {
        int k = off >> 1;
        if (k < 197) {
          int a1 = (k == 0) ? 14 : (k - 1) / 14;
          int a2 = (k == 0) ? 14 : (k - 1) % 14;
          if (row < 16) { if (row == a1) v = 0x3F80; }
          else          { if (row - 16 == a2) v = 0x3F80; }
        }
        break;
      }
    }
    gM[j] = v;
  }
  for (int j = threadIdx.x; j < 7168; j += 256) {
    int b = 2 * j;
    int row = b >> 6;
    int off = (b & 63) ^ (((row >> 1) & 3) << 4);
    int tcol = off >> 1;
    u16 v = 0;
    if (row < 197) {
      int a1 = (row == 0) ? 14 : (row - 1) / 14;
      int a2 = (row == 0) ? 14 : (row - 1) % 14;
      if (tcol < 16) { if (tcol == a1) v = 0x3F80; }
      else           { if (tcol - 16 == a2) v = 0x3F80; }
    }
    gMT[j] = v;
  }
}

// ---------------------------------------------------------------------------
// Split-bf16 MFMA GEMM (unchanged r14/r15): 8 waves, 64x32 sub-tile/wave.
// ---------------------------------------------------------------------------
template<int OSPLIT>
__global__ __launch_bounds__(512, 4) void k_gemm_mfma(
    const u16* __restrict__ Ahi, const u16* __restrict__ Alo,
    const u16* __restrict__ Bhi, const u16* __restrict__ Blo,
    const float* __restrict__ bias, float* __restrict__ Cc,
    u16* __restrict__ Chi, u16* __restrict__ Clo,
    int M, int Nc, int NT) {
  __shared__ u16 AsH[128][64];
  __shared__ u16 AsL[128][64];
  __shared__ u16 BsH[128][64];
  __shared__ u16 BsL[128][64];
  int t = threadIdx.x, w = t >> 6, l = t & 63;

  int nwg = gridDim.x, bid = blockIdx.x;
  int q8 = nwg >> 3, r8 = nwg & 7;
  int xcd = bid & 7, j8 = bid >> 3;
  int wgid = (xcd < r8 ? xcd * (q8 + 1) : r8 * (q8 + 1) + (xcd - r8) * q8) + j8;
  int mt = wgid / NT, nt = wgid - mt * NT;
  int m0 = mt * 128, n0 = nt * 128;

  int wr = w & 1, wc = w >> 1;
  f32x4 acc[4][2] = {};
  int srow = l >> 3;
  int scol = ((l & 7) ^ srow) * 8;

  for (int k0 = 0; k0 < 640; k0 += 64) {
    for (int i = w; i < 16; i += 8) {
      int row = 8 * i + srow;
      int ga = m0 + row; if (ga >= M) ga = M - 1;
      size_t offA = (size_t)ga * 640 + k0 + scol;
      size_t offB = (size_t)(n0 + row) * 640 + k0 + scol;
      __builtin_amdgcn_global_load_lds(
          (const __attribute__((address_space(1))) void*)(Ahi + offA),
          (__attribute__((address_space(3))) void*)(&AsH[8 * i][0]), 16, 0, 0);
      __builtin_amdgcn_global_load_lds(
          (const __attribute__((address_space(1))) void*)(Alo + offA),
          (__attribute__((address_space(3))) void*)(&AsL[8 * i][0]), 16, 0, 0);
      __builtin_amdgcn_global_load_lds(
          (const __attribute__((address_space(1))) void*)(Bhi + offB),
          (__attribute__((address_space(3))) void*)(&BsH[8 * i][0]), 16, 0, 0);
      __builtin_amdgcn_global_load_lds(
          (const __attribute__((address_space(1))) void*)(Blo + offB),
          (__attribute__((address_space(3))) void*)(&BsL[8 * i][0]), 16, 0, 0);
    }
    __syncthreads();
    int fr = l & 15, fq = l >> 4;
    const unsigned char* pAH = (const unsigned char*)&AsH[0][0];
    const unsigned char* pAL = (const unsigned char*)&AsL[0][0];
    const unsigned char* pBH = (const unsigned char*)&BsH[0][0];
    const unsigned char* pBL = (const unsigned char*)&BsL[0][0];
    int fsw = (fr & 7) << 4;
    #pragma unroll
    for (int ks = 0; ks < 2; ++ks) {
      int cbyte = (ks * 64 + fq * 16) ^ fsw;
      bf16x8 ah[4], al[4], bh[2], bl[2];
      #pragma unroll
      for (int mi = 0; mi < 4; ++mi) {
        int ra = (wr * 64 + 16 * mi + fr) * 128 + cbyte;
        ah[mi] = *(const bf16x8*)(pAH + ra);
        al[mi] = *(const bf16x8*)(pAL + ra);
      }
      #pragma unroll
      for (int ni = 0; ni < 2; ++ni) {
        int rb = (wc * 32 + 16 * ni + fr) * 128 + cbyte;
        bh[ni] = *(const bf16x8*)(pBH + rb);
        bl[ni] = *(const bf16x8*)(pBL + rb);
      }
      #pragma unroll
      for (int mi = 0; mi < 4; ++mi)
        #pragma unroll
        for (int ni = 0; ni < 2; ++ni) {
          acc[mi][ni] = __builtin_amdgcn_mfma_f32_16x16x32_bf16(ah[mi], bh[ni], acc[mi][ni], 0, 0, 0);
          acc[mi][ni] = __builtin_amdgcn_mfma_f32_16x16x32_bf16(al[mi], bh[ni], acc[mi][ni], 0, 0, 0);
          acc[mi][ni] = __builtin_amdgcn_mfma_f32_16x16x32_bf16(ah[mi], bl[ni], acc[mi][ni], 0, 0, 0);
        }
    }
    __syncthreads();
  }

  int fr = l & 15, fq = l >> 4;
  #pragma unroll
  for (int mi = 0; mi < 4; ++mi) {
    #pragma unroll
    for (int ni = 0; ni < 2; ++ni) {
      int col = n0 + wc * 32 + 16 * ni + fr;
      float bv = bias[col];
      #pragma unroll
      for (int r = 0; r < 4; ++r) {
        int row = m0 + wr * 64 + 16 * mi + fq * 4 + r;
        if (row < M) {
          float val = acc[mi][ni][r] + bv;
          if (OSPLIT) {
            u16 hh, ll; split_bf16(val, hh, ll);
            Chi[(size_t)row * Nc + col] = hh;
            Clo[(size_t)row * Nc + col] = ll;
          } else {
            Cc[(size_t)row * Nc + col] = val;
          }
        }
      }
    }
  }
}

// ---------------------------------------------------------------------------
// Fused MFMA attention v10: 1024 threads = 16 waves = 4 waves/SIMD (occupancy
// by geometry; r9 retried with rule-#20 fixes: ALL loops compile-time bounded,
// every sacc index literal via explicit kh branches -> no scratch).
// wave = (qgrp = w&7, kh = w>>3). kh0: score frags 0..8; kh1: frags 9..12 +
// table frags 13..16. sacc[9] = 36 AGPR. Rel-k via Pshift MFMA (gMT); buckets
// via gM MFMA; W/BvBh naturally kh-split (om half per kh). 6 barriers.
// LDS 157,696 B:
//   [0,69632)       Akhi+Aklo [272][64]u16 swz | post-B4: Pm[128][448B] swz
//   [69632,112640)  VhM[96][224]u16 swz (rows 64..95 = M one-hot)
//   [112640,120832) TvT[64][64]bf16 swz
//   [120832,141312) PvB[128]x160B | post-B5: BvBh[128] stride34 f32
//   [141312,155648) MTl[224][64B] | post-B5: Wb[128][128B] (16384, overlaps
//   [155648,157696) mpart[128][2]f32 + spart[128][2]f32    mpart/spart: safe,
//                                            last spart read is pre-B5)
// ---------------------------------------------------------------------------
__global__ __launch_bounds__(1024, 4) void k_attn(
    const u16* __restrict__ qkvhi, const u16* __restrict__ qkvlo,
    const u16* __restrict__ tabKhi, const u16* __restrict__ tabKlo,
    const u16* __restrict__ gM, const u16* __restrict__ gMT,
    const float* __restrict__ tvv, const float* __restrict__ tvh,
    u16* __restrict__ ohi, u16* __restrict__ olo) {
  __shared__ __align__(16) unsigned char LDS[157696];
  unsigned char* Akhi = LDS;
  unsigned char* Aklo = LDS + 34816;
  unsigned char* VhM  = LDS + 69632;
  unsigned char* TvT  = LDS + 112640;
  unsigned char* PvB  = LDS + 120832;
  float* BvBh = (float*)(LDS + 120832);      // [128] stride 34 f32
  unsigned char* MTl  = LDS + 141312;        // S phase
  unsigned char* Wb   = LDS + 141312;        // post-B5
  float* mpart = (float*)(LDS + 155648);     // [128][2]
  float* spart = (float*)(LDS + 156672);     // [128][2]
  unsigned char* Pm   = LDS;                 // post-B4

  int bh = blockIdx.x, b = bh / HH, h = bh % HH, qt = blockIdx.y;
  int t = threadIdx.x, w = t >> 6, l = t & 63;
  int fr = l & 15, fq = l >> 4;
  int qgrp = w & 7, kh = w >> 3;
  int q0 = 128 * qt;
  const size_t qbase = (size_t)(b * NN) * C3;

  // ---- staging ----
  int kr = l >> 3;
  int chunk = ((l & 7) ^ (kr & 7)) * 8;
  for (int i = w; i < 34; i += 16) {
    int rr = 8 * i + kr;
    const u16 *sh, *sl;
    if (rr < 208) {
      int kk = rr > 196 ? 196 : rr;
      sh = qkvhi + qbase + (size_t)kk * C3 + CC + h * DD + chunk;
      sl = qkvlo + qbase + (size_t)kk * C3 + CC + h * DD + chunk;
    } else {
      int tr = rr - 208;
      sh = tabKhi + tr * 64 + chunk;
      sl = tabKlo + tr * 64 + chunk;
    }
    __builtin_amdgcn_global_load_lds(
        (const __attribute__((address_space(1))) void*)sh,
        (__attribute__((address_space(3))) void*)(Akhi + i * 1024), 16, 0, 0);
    __builtin_amdgcn_global_load_lds(
        (const __attribute__((address_space(1))) void*)sl,
        (__attribute__((address_space(3))) void*)(Aklo + i * 1024), 16, 0, 0);
  }
  for (int i = w; i < 14; i += 16) {
    __builtin_amdgcn_global_load_lds(
        (const __attribute__((address_space(1))) void*)(gM + i * 512 + l * 8),
        (__attribute__((address_space(3))) void*)(VhM + 28672 + i * 1024), 16, 0, 0);
  }
  for (int i = w; i < 14; i += 16) {
    __builtin_amdgcn_global_load_lds(
        (const __attribute__((address_space(1))) void*)(gMT + i * 512 + l * 8),
        (__attribute__((address_space(3))) void*)(MTl + i * 1024), 16, 0, 0);
  }
  for (int idx = t; idx < 1576; idx += 1024) {
    int k = idx >> 3, d0v = (idx & 7) * 8;
    size_t off = qbase + (size_t)k * C3 + 2 * CC + h * DD + d0v;
    uint4 vh4 = *(const uint4*)(qkvhi + off);
    u16 eh[8] = {(u16)vh4.x, (u16)(vh4.x >> 16), (u16)vh4.y, (u16)(vh4.y >> 16),
                 (u16)vh4.z, (u16)(vh4.z >> 16), (u16)vh4.w, (u16)(vh4.w >> 16)};
    #pragma unroll
    for (int jj = 0; jj < 8; ++jj) {
      int d = d0v + jj;
      int byte = (d * 224 + k) * 2; byte ^= (((d & 7) ^ ((d >> 3) & 7)) << 4);
      *(u16*)(VhM + byte) = eh[jj];
    }
  }
  for (int idx = t; idx < 64 * 27; idx += 1024) {
    int d = idx / 27, k = 197 + idx % 27;
    int byte = (d * 224 + k) * 2; byte ^= (((d & 7) ^ ((d >> 3) & 7)) << 4);
    *(u16*)(VhM + byte) = 0;
  }
  for (int i = t; i < 4096; i += 1024) {
    int d = i >> 6, tt = i & 63;
    float vv = 0.f;
    if (tt < 30) vv = tvv[tt * 64 + d];
    else if (tt >= 32 && tt < 62) vv = tvh[(tt - 32) * 64 + d];
    int byte = (d * 64 + tt) * 2; byte ^= (((d & 7) ^ ((d >> 3) & 7)) << 4);
    *(u16*)(TvT + byte) = bf16rn(vv);
  }
  bool active = (q0 + 16 * qgrp) < NN;
  bf16x8 qh[2], ql_[2];
  {
    int qg = q0 + 16 * qgrp + fr; int qc = qg > 196 ? 196 : qg;
    const u16* qr  = qkvhi + qbase + (size_t)qc * C3 + h * DD;
    const u16* qr2 = qkvlo + qbase + (size_t)qc * C3 + h * DD;
    qh[0]  = *(const bf16x8*)(qr + 8 * fq);
    qh[1]  = *(const bf16x8*)(qr + 32 + 8 * fq);
    ql_[0] = *(const bf16x8*)(qr2 + 8 * fq);
    ql_[1] = *(const bf16x8*)(qr2 + 32 + 8 * fq);
  }
  __syncthreads();   // B1: staging done

  // ---- S-phase: own frags only, fully static per kh branch ----
  f32x4 sacc[9] = {};
  if (active) {
    if (kh == 0) {
      #pragma unroll
      for (int ks = 0; ks < 2; ++ks)
        #pragma unroll
        for (int nf = 0; nf < 9; ++nf) {
          int row = 16 * nf + fr;
          int byte = row * 128 + 64 * ks + 16 * fq; byte ^= (row & 7) << 4;
          bf16x8 kf = *(const bf16x8*)(Akhi + byte);
          bf16x8 lf = *(const bf16x8*)(Aklo + byte);
          sacc[nf] = __builtin_amdgcn_mfma_f32_16x16x32_bf16(qh[ks],  kf, sacc[nf], 0, 0, 0);
          sacc[nf] = __builtin_amdgcn_mfma_f32_16x16x32_bf16(ql_[ks], kf, sacc[nf], 0, 0, 0);
          sacc[nf] = __builtin_amdgcn_mfma_f32_16x16x32_bf16(qh[ks],  lf, sacc[nf], 0, 0, 0);
        }
    } else {
      #pragma unroll
      for (int ks = 0; ks < 2; ++ks)
        #pragma unroll
        for (int j = 0; j < 8; ++j) {
          int row = 16 * (9 + j) + fr;
          int byte = row * 128 + 64 * ks + 16 * fq; byte ^= (row & 7) << 4;
          bf16x8 kf = *(const bf16x8*)(Akhi + byte);
          bf16x8 lf = *(const bf16x8*)(Aklo + byte);
          sacc[j] = __builtin_amdgcn_mfma_f32_16x16x32_bf16(qh[ks],  kf, sacc[j], 0, 0, 0);
          sacc[j] = __builtin_amdgcn_mfma_f32_16x16x32_bf16(ql_[ks], kf, sacc[j], 0, 0, 0);
          sacc[j] = __builtin_amdgcn_mfma_f32_16x16x32_bf16(qh[ks],  lf, sacc[j], 0, 0, 0);
        }
      // table frags j=4..7 (nf 13..16) -> PvB stride 160
      #pragma unroll
      for (int j = 4; j < 8; ++j)
        #pragma unroll
        for (int r = 0; r < 4; ++r) {
          int c = 16 * (j - 4) + fr;
          if (c < 60) {
            int row = 16 * qgrp + 4 * fq + r;
            *(u16*)(PvB + row * 160 + 2 * c) = bf16rn(sacc[j][r]);
          }
        }
    }
  }
  __syncthreads();   // B2: PvB ready, all Ak reads done

  // ---- Pshift build + rel-k MFMA + mask/scale + partial max ----
  if (active) {
    bf16x8 psf;
    {
      int qrow = 16 * qgrp + fr;
      int qg2 = q0 + qrow; int qc2 = qg2 > 196 ? 196 : qg2;
      const unsigned char* rowb = PvB + qrow * 160;
      u16 tmp[8];
      if (qc2 == 0) {
        u16 v0 = *(const u16*)(rowb);
        u16 h0 = *(const u16*)(rowb + 60);
        #pragma unroll
        for (int j = 0; j < 8; ++j) tmp[j] = (8 * fq + j < 16) ? v0 : h0;
      } else {
        int gq2 = (qc2 - 1) / 14, cq2 = (qc2 - 1) % 14;
        #pragma unroll
        for (int j = 0; j < 8; ++j) {
          int tt2 = 8 * fq + j;
          u16 v = 0;
          if (tt2 < 14)       v = *(const u16*)(rowb + 2 * (tt2 - gq2 + 15));
          else if (tt2 == 14) v = *(const u16*)(rowb);
          else if (tt2 >= 16 && tt2 < 30) v = *(const u16*)(rowb + 60 + 2 * (tt2 - 16 - cq2 + 15));
          else if (tt2 == 30) v = *(const u16*)(rowb + 60);
          tmp[j] = v;
        }
      }
      unsigned p0 = tmp[0] | ((unsigned)tmp[1] << 16);
      unsigned p1 = tmp[2] | ((unsigned)tmp[3] << 16);
      unsigned p2 = tmp[4] | ((unsigned)tmp[5] << 16);
      unsigned p3 = tmp[6] | ((unsigned)tmp[7] << 16);
      uint4 pk = make_uint4(p0, p1, p2, p3);
      psf = *(const bf16x8*)&pk;
    }
    float mrow[4] = {-1e30f, -1e30f, -1e30f, -1e30f};
    if (kh == 0) {
      #pragma unroll
      for (int nf = 0; nf < 9; ++nf) {
        int row = 16 * nf + fr;
        int byte = row * 64 + 16 * fq; byte ^= (((row >> 1) & 3) << 4);
        bf16x8 mtf = *(const bf16x8*)(MTl + byte);
        sacc[nf] = __builtin_amdgcn_mfma_f32_16x16x32_bf16(psf, mtf, sacc[nf], 0, 0, 0);
      }
      #pragma unroll
      for (int nf = 0; nf < 9; ++nf)       // k = 16nf+fr <= 143, all valid
        #pragma unroll
        for (int r = 0; r < 4; ++r) {
          float s = sacc[nf][r] * SCALE;
          sacc[nf][r] = s;
          mrow[r] = fmaxf(mrow[r], s);
        }
    } else {
      #pragma unroll
      for (int j = 0; j < 4; ++j) {
        int row = 16 * (9 + j) + fr;
        int byte = row * 64 + 16 * fq; byte ^= (((row >> 1) & 3) << 4);
        bf16x8 mtf = *(const bf16x8*)(MTl + byte);
        sacc[j] = __builtin_amdgcn_mfma_f32_16x16x32_bf16(psf, mtf, sacc[j], 0, 0, 0);
      }
      #pragma unroll
      for (int j = 0; j < 4; ++j) {
        bool vk = (j < 3) || (fr < 5);     // k = 144+16j+fr; j=3 -> 192+fr
        #pragma unroll
        for (int r = 0; r < 4; ++r) {
          float s = vk ? sacc[j][r] * SCALE : -1e30f;
          sacc[j][r] = s;
          mrow[r] = fmaxf(mrow[r], s);
        }
      }
    }
    #pragma unroll
    for (int r = 0; r < 4; ++r)
      #pragma unroll
      for (int mk = 1; mk < 16; mk <<= 1) mrow[r] = fmaxf(mrow[r], __shfl_xor(mrow[r], mk));
    if (fr == 0) {
      #pragma unroll
      for (int r = 0; r < 4; ++r) mpart[(16 * qgrp + 4 * fq + r) * 2 + kh] = mrow[r];
    }
  }
  __syncthreads();   // B3: partial maxes ready

  // ---- exp (global max) + partial sum ----
  if (active) {
    float ssum[4] = {0.f, 0.f, 0.f, 0.f};
    float gm[4];
    #pragma unroll
    for (int r = 0; r < 4; ++r) {
      int qrl = 16 * qgrp + 4 * fq + r;
      gm[r] = fmaxf(mpart[qrl * 2], mpart[qrl * 2 + 1]);
    }
    if (kh == 0) {
      #pragma unroll
      for (int nf = 0; nf < 9; ++nf)
        #pragma unroll
        for (int r = 0; r < 4; ++r) {
          float e = __expf(sacc[nf][r] - gm[r]);
          sacc[nf][r] = e;
          ssum[r] += e;
        }
    } else {
      #pragma unroll
      for (int j = 0; j < 4; ++j)
        #pragma unroll
        for (int r = 0; r < 4; ++r) {
          float e = __expf(sacc[j][r] - gm[r]);
          sacc[j][r] = e;
          ssum[r] += e;
        }
    }
    #pragma unroll
    for (int r = 0; r < 4; ++r)
      #pragma unroll
      for (int mk = 1; mk < 16; mk <<= 1) ssum[r] += __shfl_xor(ssum[r], mk);
    if (fr == 0) {
      #pragma unroll
      for (int r = 0; r < 4; ++r) spart[(16 * qgrp + 4 * fq + r) * 2 + kh] = ssum[r];
    }
  }
  __syncthreads();   // B4: partial sums ready

  // ---- P write (own frags; static; zeros for pad/inactive) ----
  {
    float inv[4] = {0.f, 0.f, 0.f, 0.f};
    if (active) {
      #pragma unroll
      for (int r = 0; r < 4; ++r) {
        int qrl = 16 * qgrp + 4 * fq + r;
        inv[r] = 1.f / (spart[qrl * 2] + spart[qrl * 2 + 1]);
      }
    }
    if (kh == 0) {
      #pragma unroll
      for (int nf = 0; nf < 9; ++nf)
        #pragma unroll
        for (int r = 0; r < 4; ++r) {
          int k = 16 * nf + fr;
          int row = 16 * qgrp + 4 * fq + r;
          float p = active ? sacc[nf][r] * inv[r] : 0.f;
          int byte = row * 448 + 2 * k; byte ^= (((row & 7) ^ ((row >> 3) & 7)) << 4);
          *(u16*)(Pm + byte) = bf16rn(p);
        }
    } else {
      #pragma unroll
      for (int j = 0; j < 5; ++j)
        #pragma unroll
        for (int r = 0; r < 4; ++r) {
          int k = 144 + 16 * j + fr;
          int row = 16 * qgrp + 4 * fq + r;
          float p = 0.f;
          if (active && j < 4 && k < 197) p = sacc[j][r] * inv[r];
          int byte = row * 448 + 2 * k; byte ^= (((row & 7) ^ ((row >> 3) & 7)) << 4);
          *(u16*)(Pm + byte) = bf16rn(p);
        }
    }
  }
  __syncthreads();   // B5: P complete everywhere

  // ---- AV + bucket MFMA: wave (qgrp,kh) -> d-frags {2kh,2kh+1}, M-frag kh ----
  int prow = 16 * qgrp + fr;
  int pswz = ((prow & 7) ^ ((prow >> 3) & 7)) << 4;
  int vrow0 = 32 * kh + fr, vrow1 = vrow0 + 16;
  int vswz0 = ((vrow0 & 7) ^ ((vrow0 >> 3) & 7)) << 4;
  int vswz1 = ((vrow1 & 7) ^ ((vrow1 >> 3) & 7)) << 4;
  int mr2 = 64 + 16 * kh + fr;
  int mswz = ((mr2 & 7) ^ ((mr2 >> 3) & 7)) << 4;
  f32x4 ov0 = {}, ov1 = {}, om = {};
  #pragma unroll
  for (int ks = 0; ks < 7; ++ks) {
    int co = 64 * ks + 16 * fq;
    bf16x8 pah = *(const bf16x8*)(Pm + ((prow * 448 + co) ^ pswz));
    bf16x8 v0 = *(const bf16x8*)(VhM + ((vrow0 * 448 + co) ^ vswz0));
    bf16x8 v1 = *(const bf16x8*)(VhM + ((vrow1 * 448 + co) ^ vswz1));
    bf16x8 mv = *(const bf16x8*)(VhM + ((mr2 * 448 + co) ^ mswz));
    ov0 = __builtin_amdgcn_mfma_f32_16x16x32_bf16(pah, v0, ov0, 0, 0, 0);
    ov1 = __builtin_amdgcn_mfma_f32_16x16x32_bf16(pah, v1, ov1, 0, 0, 0);
    om  = __builtin_amdgcn_mfma_f32_16x16x32_bf16(pah, mv, om, 0, 0, 0);
  }
  #pragma unroll
  for (int r = 0; r < 4; ++r)
    BvBh[(16 * qgrp + 4 * fq + r) * 34 + 16 * kh + fr] = om[r];
  // (no barrier: W build below reads only this wave's BvBh half)

  // ---- W build (wave-local, own t-half = kh) ----
  {
    int row = 16 * qgrp + (l >> 2);
    int colblk = l & 3;
    if ((colblk >> 1) == kh) {
      int qg = q0 + row;
      int u0 = (colblk & 1) * 16;
      const float* bb = &BvBh[row * 34 + 16 * kh];
      u16 wv[16];
      if (qg == 0) {
        float s = 0.f;
        #pragma unroll
        for (int a = 0; a < 15; ++a) s += bb[a];
        u16 sv = bf16rn(s);
        #pragma unroll
        for (int j = 0; j < 16; ++j) wv[j] = (u0 + j == 0) ? sv : (u16)0;
      } else if (qg < NN) {
        int m = qg - 1;
        int sel = kh ? (m % 14) : (m / 14);
        #pragma unroll
        for (int j = 0; j < 16; ++j) {
          int u = u0 + j;
          float val;
          if (u == 0) val = bb[14];
          else {
            int a = u - 15 + sel;
            val = (a >= 0 && a < 14) ? bb[a] : 0.f;
          }
          wv[j] = bf16rn(val);
        }
      } else {
        #pragma unroll
        for (int j = 0; j < 16; ++j) wv[j] = 0;
      }
      uint4 p0;
      p0.x = wv[0]  | ((unsigned)wv[1]  << 16);
      p0.y = wv[2]  | ((unsigned)wv[3]  << 16);
      p0.z = wv[4]  | ((unsigned)wv[5]  << 16);
      p0.w = wv[6]  | ((unsigned)wv[7]  << 16);
      uint4 p1;
      p1.x = wv[8]  | ((unsigned)wv[9]  << 16);
      p1.y = wv[10] | ((unsigned)wv[11] << 16);
      p1.z = wv[12] | ((unsigned)wv[13] << 16);
      p1.w = wv[14] | ((unsigned)wv[15] << 16);
      int base = row * 128 + colblk * 32;
      int sz = ((row & 7) ^ ((row >> 3) & 7)) << 4;
      *(uint4*)(Wb + (base ^ sz)) = p0;
      *(uint4*)(Wb + ((base + 16) ^ sz)) = p1;
    }
  }
  __syncthreads();   // B6: W complete (both halves)

  // ---- rel-v MFMA + store ----
  f32x4 rv0 = {}, rv1 = {};
  #pragma unroll
  for (int ks2 = 0; ks2 < 2; ++ks2) {
    int co = 64 * ks2 + 16 * fq;
    bf16x8 wa = *(const bf16x8*)(Wb + ((prow * 128 + co) ^ pswz));
    bf16x8 t0 = *(const bf16x8*)(TvT + ((vrow0 * 128 + co) ^ vswz0));
    bf16x8 t1 = *(const bf16x8*)(TvT + ((vrow1 * 128 + co) ^ vswz1));
    rv0 = __builtin_amdgcn_mfma_f32_16x16x32_bf16(wa, t0, rv0, 0, 0, 0);
    rv1 = __builtin_amdgcn_mfma_f32_16x16x32_bf16(wa, t1, rv1, 0, 0, 0);
  }
  #pragma unroll
  for (int r = 0; r < 4; ++r) {
    int qrl = 16 * qgrp + 4 * fq + r;
    int qg = q0 + qrl;
    if (qg >= NN) continue;
    size_t ob = (size_t)(b * NN + qg) * CC + h * DD;
    int d0 = 32 * kh + fr, d1 = d0 + 16;
    float o0 = ov0[r] + rv0[r];
    float o1 = ov1[r] + rv1[r];
    u16 hh, ll;
    split_bf16(o0, hh, ll); ohi[ob + d0] = hh; olo[ob + d0] = ll;
    split_bf16(o1, hh, ll); ohi[ob + d1] = hh; olo[ob + d1] = ll;
  }
}

// ---------------------------------------------------------------------------
// Workspace (u16 units, ~135.7 MB):
//   qkvhi 24,207,360 | qkvlo 24,207,360 | xhi/xlo 2x8,069,120 (reused ohi/olo)
//   weffhi/lo 2x1,228,800 | wphi/lo 2x409,600 | tabKhi/lo 2x4,096
//   gM 7,168 | gMT 7,168
// ---------------------------------------------------------------------------
extern "C" void kernel_launch(void* const* d_in, const int* in_sizes, int n_in,
                              void* d_out, int out_size, void* d_ws, size_t ws_size,
                              hipStream_t stream) {
  (void)in_sizes; (void)n_in; (void)out_size; (void)ws_size;
  const float* x     = (const float*)d_in[0];
  const float* w_qkv = (const float*)d_in[1];
  const float* b_qkv = (const float*)d_in[2];
  const float* la    = (const float*)d_in[3];
  const float* lb    = (const float*)d_in[4];
  const float* tkv   = (const float*)d_in[5];
  const float* tkh   = (const float*)d_in[6];
  const float* tvv   = (const float*)d_in[7];
  const float* tvh   = (const float*)d_in[8];
  const float* wp    = (const float*)d_in[9];
  const float* b_p   = (const float*)d_in[10];

  u16* qkvhi  = (u16*)d_ws;
  u16* qkvlo  = qkvhi + (size_t)24207360;
  u16* xhi    = qkvlo + (size_t)24207360;
  u16* xlo    = xhi + (size_t)8069120;
  u16* ohi    = xhi;                       // alias (x splits dead after gemm1)
  u16* olo    = xlo;
  u16* weffhi = xlo + (size_t)8069120;
  u16* wefflo = weffhi + (size_t)1228800;
  u16* wphi   = wefflo + (size_t)1228800;
  u16* wplo   = wphi + (size_t)409600;
  u16* tabKhi = wplo + (size_t)409600;
  u16* tabKlo = tabKhi + (size_t)4096;
  u16* gM     = tabKlo + (size_t)4096;
  u16* gMT    = gM + (size_t)7168;

  k_weff<<<(C3 * CC) / 256, 256, 0, stream>>>(w_qkv, la, lb, weffhi, wefflo);
  k_cvtw<<<(CC * CC) / 256, 256, 0, stream>>>(wp, wphi, wplo);
  k_prep<<<1, 256, 0, stream>>>(tkv, tkh, tabKhi, tabKlo, gM, gMT);
  int n4x = (MTOT * CC) / 4;
  k_cvt<<<(n4x + 255) / 256, 256, 0, stream>>>(x, xhi, xlo, n4x);

  // qkv = x @ weff^T + b_qkv -> split bf16 output
  int nwg1 = ((MTOT + 127) / 128) * (C3 / 128);   // 99*15 = 1485
  k_gemm_mfma<1><<<nwg1, 512, 0, stream>>>(xhi, xlo, weffhi, wefflo, b_qkv,
                                           nullptr, qkvhi, qkvlo, MTOT, C3, C3 / 128);

  // fused attention -> ohi/olo split
  k_attn<<<dim3(BB * HH, 2), 1024, 0, stream>>>(qkvhi, qkvlo, tabKhi, tabKlo, gM, gMT,
                                                tvv, tvh, ohi, olo);

  // out = o @ perm3(w_proj)^T + b_proj
  int nwg2 = ((MTOT + 127) / 128) * (CC / 128);   // 99*5 = 495
  k_gemm_mfma<0><<<nwg2, 512, 0, stream>>>(ohi, olo, wphi, wplo, b_p,
                                           (float*)d_out, nullptr, nullptr, MTOT, CC, CC / 128);
}

// Round 17
// 280.670 us; speedup vs baseline: 1.0217x; 1.0217x over previous
//
#include <hip/hip_runtime.h>
#include <math.h>

#define BB 64
#define NN 197
#define HH 10
#define DD 64
#define CC 640
#define C3 1920
#define LR 64
#define MTOT (BB*NN)          // 12608
#define SCALE 0.125f

typedef unsigned short u16;
typedef __bf16 bf16x8 __attribute__((ext_vector_type(8)));
typedef float f32x4 __attribute__((ext_vector_type(4)));

__device__ __forceinline__ void split_bf16(float f, u16& hi, u16& lo) {
  unsigned u = __float_as_uint(f);
  unsigned r = u + 0x7FFF + ((u >> 16) & 1);
  u16 hb = (u16)(r >> 16);
  float fh = __uint_as_float((unsigned)hb << 16);
  float dl = f - fh;
  unsigned u2 = __float_as_uint(dl);
  unsigned r2 = u2 + 0x7FFF + ((u2 >> 16) & 1);
  hi = hb; lo = (u16)(r2 >> 16);
}

__device__ __forceinline__ u16 bf16rn(float f) {
  unsigned u = __float_as_uint(f);
  return (u16)((u + 0x7FFF + ((u >> 16) & 1)) >> 16);
}
__device__ __forceinline__ float bf16tof(u16 v) {
  return __uint_as_float((unsigned)v << 16);
}

// ---------------------------------------------------------------------------
// K1: w_eff = perm3(w_qkv + (lora_a @ lora_b)^T) -> bf16 hi/lo split
// ---------------------------------------------------------------------------
__global__ __launch_bounds__(256) void k_weff(
    const float* __restrict__ w_qkv, const float* __restrict__ la,
    const float* __restrict__ lb, u16* __restrict__ whi, u16* __restrict__ wlo) {
  int idx = blockIdx.x * 256 + threadIdx.x;      // covers 1920*640
  int i = idx / CC, j = idx % CC;
  int src = 3 * (i % CC) + (i / CC);
  float acc = w_qkv[(size_t)src * CC + j];
  const float* laj = la + (size_t)j * LR;
  const float* lbs = lb + src;
  #pragma unroll 8
  for (int r = 0; r < LR; ++r) acc = fmaf(laj[r], lbs[(size_t)r * C3], acc);
  u16 h, l; split_bf16(acc, h, l);
  whi[idx] = h; wlo[idx] = l;
}

// fp32 -> bf16 hi/lo split
__global__ __launch_bounds__(256) void k_cvt(
    const float* __restrict__ in, u16* __restrict__ hi, u16* __restrict__ lo, int n4) {
  int i = blockIdx.x * 256 + threadIdx.x;
  if (i >= n4) return;
  float4 v = ((const float4*)in)[i];
  float f[4] = {v.x, v.y, v.z, v.w};
  ushort4 H, L;
  u16 hh, ll;
  split_bf16(f[0], hh, ll); H.x = hh; L.x = ll;
  split_bf16(f[1], hh, ll); H.y = hh; L.y = ll;
  split_bf16(f[2], hh, ll); H.z = hh; L.z = ll;
  split_bf16(f[3], hh, ll); H.w = hh; L.w = ll;
  ((ushort4*)hi)[i] = H;
  ((ushort4*)lo)[i] = L;
}

__device__ __forceinline__ int perm640(int i) {
  return (i < 214) ? 3 * i : (i < 427 ? 3 * (i - 214) + 1 : 3 * (i - 427) + 2);
}

__global__ __launch_bounds__(256) void k_cvtw(
    const float* __restrict__ wp, u16* __restrict__ hi, u16* __restrict__ lo) {
  int idx = blockIdx.x * 256 + threadIdx.x;      // covers 640*640
  int i = idx / CC, j = idx % CC;
  float v = wp[(size_t)perm640(i) * CC + j];
  u16 h, l; split_bf16(v, h, l);
  hi[idx] = h; lo[idx] = l;
}

// ---------------------------------------------------------------------------
// k_prep: (a) tabK -> bf16 hi/lo. (b) gM bucket one-hot [32t][224k] pre-
// swizzle-linearized for V-tile. (c) gMT transposed one-hot [224k][32t],
// pre-swizzle-linearized (byte ^= ((row>>1)&3)<<4).
// ---------------------------------------------------------------------------
__global__ __launch_bounds__(256) void k_prep(
    const float* __restrict__ tkv, const float* __restrict__ tkh,
    u16* __restrict__ thi, u16* __restrict__ tlo, u16* __restrict__ gM,
    u16* __restrict__ gMT) {
  for (int idx = threadIdx.x; idx < 4096; idx += 256) {
    int row = idx >> 6, d = idx & 63;
    float v = row < 30 ? tkv[row * 64 + d] : (row < 60 ? tkh[(row - 30) * 64 + d] : 0.f);
    u16 hh, ll; split_bf16(v, hh, ll);
    thi[idx] = hh; tlo[idx] = ll;
  }
  for (int j = threadIdx.x; j < 7168; j += 256) {
    int b = 2 * j;
    u16 v = 0;
    int r0 = b / 448;
    for (int dr = -1; dr <= 1; ++dr) {
      int row = r0 + dr;
      if (row < 0 || row >= 32) continue;
      int g = (row & 7) ^ ((row >> 3) & 7);
      int off = (b ^ (g << 4)) - row * 448;
      if (off >= 0 && off < 448) {
        int k = off >> 1;
        if (k < 197) {
          int a1 = (k == 0) ? 14 : (k - 1) / 14;
          int a2 = (k == 0) ? 14 : (k - 1) % 14;
          if (row < 16) { if (row == a1) v = 0x3F80; }
          else          { if (row - 16 == a2) v = 0x3F80; }
        }
        break;
      }
    }
    gM[j] = v;
  }
  for (int j = threadIdx.x; j < 7168; j += 256) {
    int b = 2 * j;
    int row = b >> 6;
    int off = (b & 63) ^ (((row >> 1) & 3) << 4);
    int tcol = off >> 1;
    u16 v = 0;
    if (row < 197) {
      int a1 = (row == 0) ? 14 : (row - 1) / 14;
      int a2 = (row == 0) ? 14 : (row - 1) % 14;
      if (tcol < 16) { if (tcol == a1) v = 0x3F80; }
      else           { if (tcol - 16 == a2) v = 0x3F80; }
    }
    gMT[j] = v;
  }
}

// ---------------------------------------------------------------------------
// Split-bf16 MFMA GEMM: 8 waves, 64x32 sub-tile/wave, LDS XOR-swizzle,
// n-inner 1D grid + bijective XCD remap. Round-17: QKV-aware pass cut —
// n-tiles >= VNT (the V third of qkv) drop pass 3 (x_hi*w_lo, <=1ulp effect
// on V-hi) and skip the Clo write (V-lo never read by k_attn).
// ---------------------------------------------------------------------------
template<int OSPLIT>
__global__ __launch_bounds__(512, 4) void k_gemm_mfma(
    const u16* __restrict__ Ahi, const u16* __restrict__ Alo,
    const u16* __restrict__ Bhi, const u16* __restrict__ Blo,
    const float* __restrict__ bias, float* __restrict__ Cc,
    u16* __restrict__ Chi, u16* __restrict__ Clo,
    int M, int Nc, int NT, int VNT) {
  __shared__ u16 AsH[128][64];
  __shared__ u16 AsL[128][64];
  __shared__ u16 BsH[128][64];
  __shared__ u16 BsL[128][64];
  int t = threadIdx.x, w = t >> 6, l = t & 63;

  int nwg = gridDim.x, bid = blockIdx.x;
  int q8 = nwg >> 3, r8 = nwg & 7;
  int xcd = bid & 7, j8 = bid >> 3;
  int wgid = (xcd < r8 ? xcd * (q8 + 1) : r8 * (q8 + 1) + (xcd - r8) * q8) + j8;
  int mt = wgid / NT, nt = wgid - mt * NT;
  int m0 = mt * 128, n0 = nt * 128;
  bool vtile = (nt >= VNT);                // V third: 2-pass, no lo output

  int wr = w & 1, wc = w >> 1;
  f32x4 acc[4][2] = {};
  int srow = l >> 3;
  int scol = ((l & 7) ^ srow) * 8;

  for (int k0 = 0; k0 < 640; k0 += 64) {
    for (int i = w; i < 16; i += 8) {
      int row = 8 * i + srow;
      int ga = m0 + row; if (ga >= M) ga = M - 1;
      size_t offA = (size_t)ga * 640 + k0 + scol;
      size_t offB = (size_t)(n0 + row) * 640 + k0 + scol;
      __builtin_amdgcn_global_load_lds(
          (const __attribute__((address_space(1))) void*)(Ahi + offA),
          (__attribute__((address_space(3))) void*)(&AsH[8 * i][0]), 16, 0, 0);
      __builtin_amdgcn_global_load_lds(
          (const __attribute__((address_space(1))) void*)(Alo + offA),
          (__attribute__((address_space(3))) void*)(&AsL[8 * i][0]), 16, 0, 0);
      __builtin_amdgcn_global_load_lds(
          (const __attribute__((address_space(1))) void*)(Bhi + offB),
          (__attribute__((address_space(3))) void*)(&BsH[8 * i][0]), 16, 0, 0);
      __builtin_amdgcn_global_load_lds(
          (const __attribute__((address_space(1))) void*)(Blo + offB),
          (__attribute__((address_space(3))) void*)(&BsL[8 * i][0]), 16, 0, 0);
    }
    __syncthreads();
    int fr = l & 15, fq = l >> 4;
    const unsigned char* pAH = (const unsigned char*)&AsH[0][0];
    const unsigned char* pAL = (const unsigned char*)&AsL[0][0];
    const unsigned char* pBH = (const unsigned char*)&BsH[0][0];
    const unsigned char* pBL = (const unsigned char*)&BsL[0][0];
    int fsw = (fr & 7) << 4;
    #pragma unroll
    for (int ks = 0; ks < 2; ++ks) {
      int cbyte = (ks * 64 + fq * 16) ^ fsw;
      bf16x8 ah[4], al[4], bh[2], bl[2];
      #pragma unroll
      for (int mi = 0; mi < 4; ++mi) {
        int ra = (wr * 64 + 16 * mi + fr) * 128 + cbyte;
        ah[mi] = *(const bf16x8*)(pAH + ra);
        al[mi] = *(const bf16x8*)(pAL + ra);
      }
      #pragma unroll
      for (int ni = 0; ni < 2; ++ni) {
        int rb = (wc * 32 + 16 * ni + fr) * 128 + cbyte;
        bh[ni] = *(const bf16x8*)(pBH + rb);
        bl[ni] = *(const bf16x8*)(pBL + rb);
      }
      #pragma unroll
      for (int mi = 0; mi < 4; ++mi)
        #pragma unroll
        for (int ni = 0; ni < 2; ++ni) {
          acc[mi][ni] = __builtin_amdgcn_mfma_f32_16x16x32_bf16(ah[mi], bh[ni], acc[mi][ni], 0, 0, 0);
          acc[mi][ni] = __builtin_amdgcn_mfma_f32_16x16x32_bf16(al[mi], bh[ni], acc[mi][ni], 0, 0, 0);
          if (!vtile)
            acc[mi][ni] = __builtin_amdgcn_mfma_f32_16x16x32_bf16(ah[mi], bl[ni], acc[mi][ni], 0, 0, 0);
        }
    }
    __syncthreads();
  }

  int fr = l & 15, fq = l >> 4;
  #pragma unroll
  for (int mi = 0; mi < 4; ++mi) {
    #pragma unroll
    for (int ni = 0; ni < 2; ++ni) {
      int col = n0 + wc * 32 + 16 * ni + fr;
      float bv = bias[col];
      #pragma unroll
      for (int r = 0; r < 4; ++r) {
        int row = m0 + wr * 64 + 16 * mi + fq * 4 + r;
        if (row < M) {
          float val = acc[mi][ni][r] + bv;
          if (OSPLIT) {
            u16 hh, ll; split_bf16(val, hh, ll);
            Chi[(size_t)row * Nc + col] = hh;
            if (!vtile) Clo[(size_t)row * Nc + col] = ll;
          } else {
            Cc[(size_t)row * Nc + col] = val;
          }
        }
      }
    }
  }
}

// ---------------------------------------------------------------------------
// Fused MFMA attention v9 (r15 winner, verbatim): 512 thr, q-tile 128,
// 2 barriers, wave-local tail, Pshift-MFMA rel-k, gM-MFMA buckets.
// LDS 157,696 B.
// ---------------------------------------------------------------------------
__global__ __launch_bounds__(512, 2) void k_attn(
    const u16* __restrict__ qkvhi, const u16* __restrict__ qkvlo,
    const u16* __restrict__ tabKhi, const u16* __restrict__ tabKlo,
    const u16* __restrict__ gM, const u16* __restrict__ gMT,
    const float* __restrict__ tvv, const float* __restrict__ tvh,
    u16* __restrict__ ohi, u16* __restrict__ olo) {
  __shared__ __align__(16) unsigned char LDS[157696];
  unsigned char* Akhi = LDS;
  unsigned char* Aklo = LDS + 34816;
  unsigned char* VhM  = LDS + 69632;
  unsigned char* TvT  = LDS + 112640;
  unsigned char* PvB  = LDS + 120832;
  float* BvBh = (float*)(LDS + 120832);      // [128] stride 34 f32
  unsigned char* MTl  = LDS + 141312;        // [224][32] bf16 swz (S phase)
  unsigned char* Wb   = LDS + 141312;        // post-B2
  unsigned char* Pm   = LDS;

  int bh = blockIdx.x, b = bh / HH, h = bh % HH, qt = blockIdx.y;
  int t = threadIdx.x, w = t >> 6, l = t & 63;
  int fr = l & 15, fq = l >> 4;
  int q0 = 128 * qt;
  const size_t qbase = (size_t)(b * NN) * C3;

  int kr = l >> 3;
  int chunk = ((l & 7) ^ (kr & 7)) * 8;
  for (int i = w; i < 34; i += 8) {
    int rr = 8 * i + kr;
    const u16 *sh, *sl;
    if (rr < 208) {
      int kk = rr > 196 ? 196 : rr;
      sh = qkvhi + qbase + (size_t)kk * C3 + CC + h * DD + chunk;
      sl = qkvlo + qbase + (size_t)kk * C3 + CC + h * DD + chunk;
    } else {
      int tr = rr - 208;
      sh = tabKhi + tr * 64 + chunk;
      sl = tabKlo + tr * 64 + chunk;
    }
    __builtin_amdgcn_global_load_lds(
        (const __attribute__((address_space(1))) void*)sh,
        (__attribute__((address_space(3))) void*)(Akhi + i * 1024), 16, 0, 0);
    __builtin_amdgcn_global_load_lds(
        (const __attribute__((address_space(1))) void*)sl,
        (__attribute__((address_space(3))) void*)(Aklo + i * 1024), 16, 0, 0);
  }
  for (int i = w; i < 14; i += 8) {
    __builtin_amdgcn_global_load_lds(
        (const __attribute__((address_space(1))) void*)(gM + i * 512 + l * 8),
        (__attribute__((address_space(3))) void*)(VhM + 28672 + i * 1024), 16, 0, 0);
  }
  for (int i = w; i < 14; i += 8) {
    __builtin_amdgcn_global_load_lds(
        (const __attribute__((address_space(1))) void*)(gMT + i * 512 + l * 8),
        (__attribute__((address_space(3))) void*)(MTl + i * 1024), 16, 0, 0);
  }
  for (int idx = t; idx < 1576; idx += 512) {
    int k = idx >> 3, d0v = (idx & 7) * 8;
    size_t off = qbase + (size_t)k * C3 + 2 * CC + h * DD + d0v;
    uint4 vh4 = *(const uint4*)(qkvhi + off);
    u16 eh[8] = {(u16)vh4.x, (u16)(vh4.x >> 16), (u16)vh4.y, (u16)(vh4.y >> 16),
                 (u16)vh4.z, (u16)(vh4.z >> 16), (u16)vh4.w, (u16)(vh4.w >> 16)};
    #pragma unroll
    for (int jj = 0; jj < 8; ++jj) {
      int d = d0v + jj;
      int byte = (d * 224 + k) * 2; byte ^= (((d & 7) ^ ((d >> 3) & 7)) << 4);
      *(u16*)(VhM + byte) = eh[jj];
    }
  }
  for (int idx = t; idx < 64 * 27; idx += 512) {
    int d = idx / 27, k = 197 + idx % 27;
    int byte = (d * 224 + k) * 2; byte ^= (((d & 7) ^ ((d >> 3) & 7)) << 4);
    *(u16*)(VhM + byte) = 0;
  }
  for (int i = t; i < 4096; i += 512) {
    int d = i >> 6, tt = i & 63;
    float vv = 0.f;
    if (tt < 30) vv = tvv[tt * 64 + d];
    else if (tt >= 32 && tt < 62) vv = tvh[(tt - 32) * 64 + d];
    int byte = (d * 64 + tt) * 2; byte ^= (((d & 7) ^ ((d >> 3) & 7)) << 4);
    *(u16*)(TvT + byte) = bf16rn(vv);
  }
  bool active = (q0 + 16 * w) < NN;
  bf16x8 qh[2], ql_[2];
  {
    int qg = q0 + 16 * w + fr; int qc = qg > 196 ? 196 : qg;
    const u16* qr  = qkvhi + qbase + (size_t)qc * C3 + h * DD;
    const u16* qr2 = qkvlo + qbase + (size_t)qc * C3 + h * DD;
    qh[0]  = *(const bf16x8*)(qr + 8 * fq);
    qh[1]  = *(const bf16x8*)(qr + 32 + 8 * fq);
    ql_[0] = *(const bf16x8*)(qr2 + 8 * fq);
    ql_[1] = *(const bf16x8*)(qr2 + 32 + 8 * fq);
  }
  __syncthreads();   // B1

  float ex[13][4];
  float inv[4];
  if (active) {
    f32x4 sacc[17] = {};
    #pragma unroll
    for (int ks = 0; ks < 2; ++ks)
      #pragma unroll
      for (int nf = 0; nf < 17; ++nf) {
        int row = 16 * nf + fr;
        int byte = row * 128 + 64 * ks + 16 * fq; byte ^= (row & 7) << 4;
        bf16x8 kf = *(const bf16x8*)(Akhi + byte);
        bf16x8 lf = *(const bf16x8*)(Aklo + byte);
        sacc[nf] = __builtin_amdgcn_mfma_f32_16x16x32_bf16(qh[ks],  kf, sacc[nf], 0, 0, 0);
        sacc[nf] = __builtin_amdgcn_mfma_f32_16x16x32_bf16(ql_[ks], kf, sacc[nf], 0, 0, 0);
        sacc[nf] = __builtin_amdgcn_mfma_f32_16x16x32_bf16(qh[ks],  lf, sacc[nf], 0, 0, 0);
      }
    #pragma unroll
    for (int nf = 13; nf < 17; ++nf)
      #pragma unroll
      for (int r = 0; r < 4; ++r) {
        int c = 16 * (nf - 13) + fr;
        if (c < 60) {
          int row = 16 * w + 4 * fq + r;
          *(u16*)(PvB + row * 160 + 2 * c) = bf16rn(sacc[nf][r]);
        }
      }
    bf16x8 psf;
    {
      int qrow = 16 * w + fr;
      int qg2 = q0 + qrow; int qc2 = qg2 > 196 ? 196 : qg2;
      const unsigned char* rowb = PvB + qrow * 160;
      u16 tmp[8];
      if (qc2 == 0) {
        u16 v0 = *(const u16*)(rowb);
        u16 h0 = *(const u16*)(rowb + 60);
        #pragma unroll
        for (int j = 0; j < 8; ++j) tmp[j] = (8 * fq + j < 16) ? v0 : h0;
      } else {
        int gq2 = (qc2 - 1) / 14, cq2 = (qc2 - 1) % 14;
        #pragma unroll
        for (int j = 0; j < 8; ++j) {
          int tt2 = 8 * fq + j;
          u16 v = 0;
          if (tt2 < 14)       v = *(const u16*)(rowb + 2 * (tt2 - gq2 + 15));
          else if (tt2 == 14) v = *(const u16*)(rowb);
          else if (tt2 >= 16 && tt2 < 30) v = *(const u16*)(rowb + 60 + 2 * (tt2 - 16 - cq2 + 15));
          else if (tt2 == 30) v = *(const u16*)(rowb + 60);
          tmp[j] = v;
        }
      }
      unsigned p0 = tmp[0] | ((unsigned)tmp[1] << 16);
      unsigned p1 = tmp[2] | ((unsigned)tmp[3] << 16);
      unsigned p2 = tmp[4] | ((unsigned)tmp[5] << 16);
      unsigned p3 = tmp[6] | ((unsigned)tmp[7] << 16);
      uint4 pk = make_uint4(p0, p1, p2, p3);
      psf = *(const bf16x8*)&pk;
    }
    #pragma unroll
    for (int nf = 0; nf < 13; ++nf) {
      int row = 16 * nf + fr;
      int byte = row * 64 + 16 * fq; byte ^= (((row >> 1) & 3) << 4);
      bf16x8 mtf = *(const bf16x8*)(MTl + byte);
      sacc[nf] = __builtin_amdgcn_mfma_f32_16x16x32_bf16(psf, mtf, sacc[nf], 0, 0, 0);
    }
    float mrow[4] = {-1e30f, -1e30f, -1e30f, -1e30f};
    #pragma unroll
    for (int nf = 0; nf < 13; ++nf) {
      int k = 16 * nf + fr;
      bool vk = k < 197;
      #pragma unroll
      for (int r = 0; r < 4; ++r) {
        float s = vk ? sacc[nf][r] * SCALE : -1e30f;
        ex[nf][r] = s;
        mrow[r] = fmaxf(mrow[r], s);
      }
    }
    #pragma unroll
    for (int r = 0; r < 4; ++r)
      #pragma unroll
      for (int mk = 1; mk < 16; mk <<= 1) mrow[r] = fmaxf(mrow[r], __shfl_xor(mrow[r], mk));
    float sum[4] = {0.f, 0.f, 0.f, 0.f};
    #pragma unroll
    for (int nf = 0; nf < 13; ++nf)
      #pragma unroll
      for (int r = 0; r < 4; ++r) {
        ex[nf][r] = __expf(ex[nf][r] - mrow[r]);
        sum[r] += ex[nf][r];
      }
    #pragma unroll
    for (int r = 0; r < 4; ++r) {
      #pragma unroll
      for (int mk = 1; mk < 16; mk <<= 1) sum[r] += __shfl_xor(sum[r], mk);
      inv[r] = 1.f / sum[r];
    }
  }
  __syncthreads();   // B2 (LAST barrier)

  #pragma unroll
  for (int nf = 0; nf < 14; ++nf)
    #pragma unroll
    for (int r = 0; r < 4; ++r) {
      int k = 16 * nf + fr;
      int row = 16 * w + 4 * fq + r;
      float p = 0.f;
      if (active && nf < 13 && k < 197) p = ex[nf][r] * inv[r];
      int byte = row * 448 + 2 * k; byte ^= (((row & 7) ^ ((row >> 3) & 7)) << 4);
      *(u16*)(Pm + byte) = bf16rn(p);
    }

  int prow = 16 * w + fr;
  int pswz = ((prow & 7) ^ ((prow >> 3) & 7)) << 4;
  f32x4 ov[4] = {};
  f32x4 om[2] = {};
  #pragma unroll
  for (int ks = 0; ks < 7; ++ks) {
    int co = 64 * ks + 16 * fq;
    bf16x8 pah = *(const bf16x8*)(Pm + ((prow * 448 + co) ^ pswz));
    #pragma unroll
    for (int nf = 0; nf < 4; ++nf) {
      int vrow = 16 * nf + fr;
      int vswz = ((vrow & 7) ^ ((vrow >> 3) & 7)) << 4;
      bf16x8 v = *(const bf16x8*)(VhM + ((vrow * 448 + co) ^ vswz));
      ov[nf] = __builtin_amdgcn_mfma_f32_16x16x32_bf16(pah, v, ov[nf], 0, 0, 0);
    }
    #pragma unroll
    for (int mf = 0; mf < 2; ++mf) {
      int mr = 64 + 16 * mf + fr;
      int mswz = ((mr & 7) ^ ((mr >> 3) & 7)) << 4;
      bf16x8 mv = *(const bf16x8*)(VhM + ((mr * 448 + co) ^ mswz));
      om[mf] = __builtin_amdgcn_mfma_f32_16x16x32_bf16(pah, mv, om[mf], 0, 0, 0);
    }
  }
  #pragma unroll
  for (int mf = 0; mf < 2; ++mf)
    #pragma unroll
    for (int r = 0; r < 4; ++r)
      BvBh[(16 * w + 4 * fq + r) * 34 + 16 * mf + fr] = om[mf][r];

  {
    int row = 16 * w + (l >> 2);
    int qg = q0 + row;
    int half = (l & 3) >> 1;
    int u0 = (l & 1) * 16;
    const float* bb = &BvBh[row * 34 + 16 * half];
    u16 wv[16];
    if (qg == 0) {
      float s = 0.f;
      #pragma unroll
      for (int a = 0; a < 15; ++a) s += bb[a];
      u16 sv = bf16rn(s);
      #pragma unroll
      for (int j = 0; j < 16; ++j) wv[j] = (u0 + j == 0) ? sv : (u16)0;
    } else if (qg < NN) {
      int m = qg - 1;
      int sel = half ? (m % 14) : (m / 14);
      #pragma unroll
      for (int j = 0; j < 16; ++j) {
        int u = u0 + j;
        float val;
        if (u == 0) val = bb[14];
        else {
          int a = u - 15 + sel;
          val = (a >= 0 && a < 14) ? bb[a] : 0.f;
        }
        wv[j] = bf16rn(val);
      }
    } else {
      #pragma unroll
      for (int j = 0; j < 16; ++j) wv[j] = 0;
    }
    uint4 p0, p1;
    p0.x = wv[0]  | ((unsigned)wv[1]  << 16);
    p0.y = wv[2]  | ((unsigned)wv[3]  << 16);
    p0.z = wv[4]  | ((unsigned)wv[5]  << 16);
    p0.w = wv[6]  | ((unsigned)wv[7]  << 16);
    p1.x = wv[8]  | ((unsigned)wv[9]  << 16);
    p1.y = wv[10] | ((unsigned)wv[11] << 16);
    p1.z = wv[12] | ((unsigned)wv[13] << 16);
    p1.w = wv[14] | ((unsigned)wv[15] << 16);
    int base = row * 128 + (l & 3) * 32;
    int sz = ((row & 7) ^ ((row >> 3) & 7)) << 4;
    *(uint4*)(Wb + (base ^ sz)) = p0;
    *(uint4*)(Wb + ((base + 16) ^ sz)) = p1;
  }

  f32x4 rv[4] = {};
  #pragma unroll
  for (int ks2 = 0; ks2 < 2; ++ks2) {
    int co = 64 * ks2 + 16 * fq;
    bf16x8 wa = *(const bf16x8*)(Wb + ((prow * 128 + co) ^ pswz));
    #pragma unroll
    for (int nf = 0; nf < 4; ++nf) {
      int vrow = 16 * nf + fr;
      int vswz = ((vrow & 7) ^ ((vrow >> 3) & 7)) << 4;
      bf16x8 tv = *(const bf16x8*)(TvT + ((vrow * 128 + co) ^ vswz));
      rv[nf] = __builtin_amdgcn_mfma_f32_16x16x32_bf16(wa, tv, rv[nf], 0, 0, 0);
    }
  }

  #pragma unroll
  for (int r = 0; r < 4; ++r) {
    int qrl = 16 * w + 4 * fq + r;
    int qg = q0 + qrl;
    if (qg >= NN) continue;
    size_t ob = (size_t)(b * NN + qg) * CC + h * DD;
    #pragma unroll
    for (int nf = 0; nf < 4; ++nf) {
      int d = 16 * nf + fr;
      float o = ov[nf][r] + rv[nf][r];
      u16 hh, ll;
      split_bf16(o, hh, ll);
      ohi[ob + d] = hh; olo[ob + d] = ll;
    }
  }
}

// ---------------------------------------------------------------------------
// Workspace (u16 units, ~135.7 MB):
//   qkvhi 24,207,360 | qkvlo 24,207,360 | xhi/xlo 2x8,069,120 (reused ohi/olo)
//   weffhi/lo 2x1,228,800 | wphi/lo 2x409,600 | tabKhi/lo 2x4,096
//   gM 7,168 | gMT 7,168
// ---------------------------------------------------------------------------
extern "C" void kernel_launch(void* const* d_in, const int* in_sizes, int n_in,
                              void* d_out, int out_size, void* d_ws, size_t ws_size,
                              hipStream_t stream) {
  (void)in_sizes; (void)n_in; (void)out_size; (void)ws_size;
  const float* x     = (const float*)d_in[0];
  const float* w_qkv = (const float*)d_in[1];
  const float* b_qkv = (const float*)d_in[2];
  const float* la    = (const float*)d_in[3];
  const float* lb    = (const float*)d_in[4];
  const float* tkv   = (const float*)d_in[5];
  const float* tkh   = (const float*)d_in[6];
  const float* tvv   = (const float*)d_in[7];
  const float* tvh   = (const float*)d_in[8];
  const float* wp    = (const float*)d_in[9];
  const float* b_p   = (const float*)d_in[10];

  u16* qkvhi  = (u16*)d_ws;
  u16* qkvlo  = qkvhi + (size_t)24207360;
  u16* xhi    = qkvlo + (size_t)24207360;
  u16* xlo    = xhi + (size_t)8069120;
  u16* ohi    = xhi;                       // alias (x splits dead after gemm1)
  u16* olo    = xlo;
  u16* weffhi = xlo + (size_t)8069120;
  u16* wefflo = weffhi + (size_t)1228800;
  u16* wphi   = wefflo + (size_t)1228800;
  u16* wplo   = wphi + (size_t)409600;
  u16* tabKhi = wplo + (size_t)409600;
  u16* tabKlo = tabKhi + (size_t)4096;
  u16* gM     = tabKlo + (size_t)4096;
  u16* gMT    = gM + (size_t)7168;

  k_weff<<<(C3 * CC) / 256, 256, 0, stream>>>(w_qkv, la, lb, weffhi, wefflo);
  k_cvtw<<<(CC * CC) / 256, 256, 0, stream>>>(wp, wphi, wplo);
  k_prep<<<1, 256, 0, stream>>>(tkv, tkh, tabKhi, tabKlo, gM, gMT);
  int n4x = (MTOT * CC) / 4;
  k_cvt<<<(n4x + 255) / 256, 256, 0, stream>>>(x, xhi, xlo, n4x);

  // qkv = x @ weff^T + b_qkv -> split bf16 output (V tiles: 2-pass, hi-only)
  int nwg1 = ((MTOT + 127) / 128) * (C3 / 128);   // 99*15 = 1485
  k_gemm_mfma<1><<<nwg1, 512, 0, stream>>>(xhi, xlo, weffhi, wefflo, b_qkv,
                                           nullptr, qkvhi, qkvlo, MTOT, C3, C3 / 128, 10);

  // fused attention -> ohi/olo split
  k_attn<<<dim3(BB * HH, 2), 512, 0, stream>>>(qkvhi, qkvlo, tabKhi, tabKlo, gM, gMT,
                                               tvv, tvh, ohi, olo);

  // out = o @ perm3(w_proj)^T + b_proj
  int nwg2 = ((MTOT + 127) / 128) * (CC / 128);   // 99*5 = 495
  k_gemm_mfma<0><<<nwg2, 512, 0, stream>>>(ohi, olo, wphi, wplo, b_p,
                                           (float*)d_out, nullptr, nullptr, MTOT, CC, CC / 128, 999);
}

// Round 18
// 272.854 us; speedup vs baseline: 1.0509x; 1.0286x over previous
//
#include <hip/hip_runtime.h>
#include <math.h>

#define BB 64
#define NN 197
#define HH 10
#define DD 64
#define CC 640
#define C3 1920
#define LR 64
#define MTOT (BB*NN)          // 12608
#define SCALE 0.125f

typedef unsigned short u16;
typedef __bf16 bf16x8 __attribute__((ext_vector_type(8)));
typedef float f32x4 __attribute__((ext_vector_type(4)));

__device__ __forceinline__ void split_bf16(float f, u16& hi, u16& lo) {
  unsigned u = __float_as_uint(f);
  unsigned r = u + 0x7FFF + ((u >> 16) & 1);
  u16 hb = (u16)(r >> 16);
  float fh = __uint_as_float((unsigned)hb << 16);
  float dl = f - fh;
  unsigned u2 = __float_as_uint(dl);
  unsigned r2 = u2 + 0x7FFF + ((u2 >> 16) & 1);
  hi = hb; lo = (u16)(r2 >> 16);
}

__device__ __forceinline__ u16 bf16rn(float f) {
  unsigned u = __float_as_uint(f);
  return (u16)((u + 0x7FFF + ((u >> 16) & 1)) >> 16);
}
__device__ __forceinline__ float bf16tof(u16 v) {
  return __uint_as_float((unsigned)v << 16);
}

__device__ __forceinline__ int perm640(int i) {
  return (i < 214) ? 3 * i : (i < 427 ? 3 * (i - 214) + 1 : 3 * (i - 427) + 2);
}

// ---------------------------------------------------------------------------
// k_prep_all: fused independent prep work (block-range dispatch, all
// concurrent; previously 4 serial kernels ~20us makespan -> ~max(11us)):
//   blocks [0, 7880):        x -> xhi/xlo split (k_cvt)
//   blocks [7880, 12680):    w_eff = perm3(w_qkv + (la@lb)^T) -> hi/lo
//   blocks [12680, 14280):   w_proj perm640 -> hi/lo
//   block  14280:            tabK hi/lo + gM + gMT
// ---------------------------------------------------------------------------
__global__ __launch_bounds__(256) void k_prep_all(
    const float* __restrict__ x, u16* __restrict__ xhi, u16* __restrict__ xlo,
    const float* __restrict__ w_qkv, const float* __restrict__ la,
    const float* __restrict__ lb, u16* __restrict__ weffhi, u16* __restrict__ wefflo,
    const float* __restrict__ wp, u16* __restrict__ wphi, u16* __restrict__ wplo,
    const float* __restrict__ tkv, const float* __restrict__ tkh,
    u16* __restrict__ thi, u16* __restrict__ tlo,
    u16* __restrict__ gM, u16* __restrict__ gMT) {
  int bid = blockIdx.x;
  if (bid < 7880) {
    // ---- x fp32 -> bf16 hi/lo (float4 granules) ----
    int i = bid * 256 + threadIdx.x;
    if (i >= (MTOT * CC) / 4) return;
    float4 v = ((const float4*)x)[i];
    float f[4] = {v.x, v.y, v.z, v.w};
    ushort4 H, L;
    u16 hh, ll;
    split_bf16(f[0], hh, ll); H.x = hh; L.x = ll;
    split_bf16(f[1], hh, ll); H.y = hh; L.y = ll;
    split_bf16(f[2], hh, ll); H.z = hh; L.z = ll;
    split_bf16(f[3], hh, ll); H.w = hh; L.w = ll;
    ((ushort4*)xhi)[i] = H;
    ((ushort4*)xlo)[i] = L;
  } else if (bid < 12680) {
    // ---- w_eff = perm3(w_qkv + (la@lb)^T) -> hi/lo ----
    int idx = (bid - 7880) * 256 + threadIdx.x;   // covers 1920*640
    int i = idx / CC, j = idx % CC;
    int src = 3 * (i % CC) + (i / CC);
    float acc = w_qkv[(size_t)src * CC + j];
    const float* laj = la + (size_t)j * LR;
    const float* lbs = lb + src;
    #pragma unroll 8
    for (int r = 0; r < LR; ++r) acc = fmaf(laj[r], lbs[(size_t)r * C3], acc);
    u16 h, l; split_bf16(acc, h, l);
    weffhi[idx] = h; wefflo[idx] = l;
  } else if (bid < 14280) {
    // ---- w_proj perm640 -> hi/lo ----
    int idx = (bid - 12680) * 256 + threadIdx.x;  // covers 640*640
    int i = idx / CC, j = idx % CC;
    float v = wp[(size_t)perm640(i) * CC + j];
    u16 h, l; split_bf16(v, h, l);
    wphi[idx] = h; wplo[idx] = l;
  } else {
    // ---- tabK + gM + gMT (single block) ----
    for (int idx = threadIdx.x; idx < 4096; idx += 256) {
      int row = idx >> 6, d = idx & 63;
      float v = row < 30 ? tkv[row * 64 + d] : (row < 60 ? tkh[(row - 30) * 64 + d] : 0.f);
      u16 hh, ll; split_bf16(v, hh, ll);
      thi[idx] = hh; tlo[idx] = ll;
    }
    for (int j = threadIdx.x; j < 7168; j += 256) {
      int b = 2 * j;
      u16 v = 0;
      int r0 = b / 448;
      for (int dr = -1; dr <= 1; ++dr) {
        int row = r0 + dr;
        if (row < 0 || row >= 32) continue;
        int g = (row & 7) ^ ((row >> 3) & 7);
        int off = (b ^ (g << 4)) - row * 448;
        if (off >= 0 && off < 448) {
          int k = off >> 1;
          if (k < 197) {
            int a1 = (k == 0) ? 14 : (k - 1) / 14;
            int a2 = (k == 0) ? 14 : (k - 1) % 14;
            if (row < 16) { if (row == a1) v = 0x3F80; }
            else          { if (row - 16 == a2) v = 0x3F80; }
          }
          break;
        }
      }
      gM[j] = v;
    }
    for (int j = threadIdx.x; j < 7168; j += 256) {
      int b = 2 * j;
      int row = b >> 6;
      int off = (b & 63) ^ (((row >> 1) & 3) << 4);
      int tcol = off >> 1;
      u16 v = 0;
      if (row < 197) {
        int a1 = (row == 0) ? 14 : (row - 1) / 14;
        int a2 = (row == 0) ? 14 : (row - 1) % 14;
        if (tcol < 16) { if (tcol == a1) v = 0x3F80; }
        else           { if (tcol - 16 == a2) v = 0x3F80; }
      }
      gMT[j] = v;
    }
  }
}

// ---------------------------------------------------------------------------
// Split-bf16 MFMA GEMM: 8 waves, 64x32 sub-tile/wave, LDS XOR-swizzle,
// n-inner 1D grid + bijective XCD remap. V-tiles (nt >= VNT): 2-pass, hi-only.
// ---------------------------------------------------------------------------
template<int OSPLIT>
__global__ __launch_bounds__(512, 4) void k_gemm_mfma(
    const u16* __restrict__ Ahi, const u16* __restrict__ Alo,
    const u16* __restrict__ Bhi, const u16* __restrict__ Blo,
    const float* __restrict__ bias, float* __restrict__ Cc,
    u16* __restrict__ Chi, u16* __restrict__ Clo,
    int M, int Nc, int NT, int VNT) {
  __shared__ u16 AsH[128][64];
  __shared__ u16 AsL[128][64];
  __shared__ u16 BsH[128][64];
  __shared__ u16 BsL[128][64];
  int t = threadIdx.x, w = t >> 6, l = t & 63;

  int nwg = gridDim.x, bid = blockIdx.x;
  int q8 = nwg >> 3, r8 = nwg & 7;
  int xcd = bid & 7, j8 = bid >> 3;
  int wgid = (xcd < r8 ? xcd * (q8 + 1) : r8 * (q8 + 1) + (xcd - r8) * q8) + j8;
  int mt = wgid / NT, nt = wgid - mt * NT;
  int m0 = mt * 128, n0 = nt * 128;
  bool vtile = (nt >= VNT);

  int wr = w & 1, wc = w >> 1;
  f32x4 acc[4][2] = {};
  int srow = l >> 3;
  int scol = ((l & 7) ^ srow) * 8;

  for (int k0 = 0; k0 < 640; k0 += 64) {
    for (int i = w; i < 16; i += 8) {
      int row = 8 * i + srow;
      int ga = m0 + row; if (ga >= M) ga = M - 1;
      size_t offA = (size_t)ga * 640 + k0 + scol;
      size_t offB = (size_t)(n0 + row) * 640 + k0 + scol;
      __builtin_amdgcn_global_load_lds(
          (const __attribute__((address_space(1))) void*)(Ahi + offA),
          (__attribute__((address_space(3))) void*)(&AsH[8 * i][0]), 16, 0, 0);
      __builtin_amdgcn_global_load_lds(
          (const __attribute__((address_space(1))) void*)(Alo + offA),
          (__attribute__((address_space(3))) void*)(&AsL[8 * i][0]), 16, 0, 0);
      __builtin_amdgcn_global_load_lds(
          (const __attribute__((address_space(1))) void*)(Bhi + offB),
          (__attribute__((address_space(3))) void*)(&BsH[8 * i][0]), 16, 0, 0);
      __builtin_amdgcn_global_load_lds(
          (const __attribute__((address_space(1))) void*)(Blo + offB),
          (__attribute__((address_space(3))) void*)(&BsL[8 * i][0]), 16, 0, 0);
    }
    __syncthreads();
    int fr = l & 15, fq = l >> 4;
    const unsigned char* pAH = (const unsigned char*)&AsH[0][0];
    const unsigned char* pAL = (const unsigned char*)&AsL[0][0];
    const unsigned char* pBH = (const unsigned char*)&BsH[0][0];
    const unsigned char* pBL = (const unsigned char*)&BsL[0][0];
    int fsw = (fr & 7) << 4;
    #pragma unroll
    for (int ks = 0; ks < 2; ++ks) {
      int cbyte = (ks * 64 + fq * 16) ^ fsw;
      bf16x8 ah[4], al[4], bh[2], bl[2];
      #pragma unroll
      for (int mi = 0; mi < 4; ++mi) {
        int ra = (wr * 64 + 16 * mi + fr) * 128 + cbyte;
        ah[mi] = *(const bf16x8*)(pAH + ra);
        al[mi] = *(const bf16x8*)(pAL + ra);
      }
      #pragma unroll
      for (int ni = 0; ni < 2; ++ni) {
        int rb = (wc * 32 + 16 * ni + fr) * 128 + cbyte;
        bh[ni] = *(const bf16x8*)(pBH + rb);
        bl[ni] = *(const bf16x8*)(pBL + rb);
      }
      #pragma unroll
      for (int mi = 0; mi < 4; ++mi)
        #pragma unroll
        for (int ni = 0; ni < 2; ++ni) {
          acc[mi][ni] = __builtin_amdgcn_mfma_f32_16x16x32_bf16(ah[mi], bh[ni], acc[mi][ni], 0, 0, 0);
          acc[mi][ni] = __builtin_amdgcn_mfma_f32_16x16x32_bf16(al[mi], bh[ni], acc[mi][ni], 0, 0, 0);
          if (!vtile)
            acc[mi][ni] = __builtin_amdgcn_mfma_f32_16x16x32_bf16(ah[mi], bl[ni], acc[mi][ni], 0, 0, 0);
        }
    }
    __syncthreads();
  }

  int fr = l & 15, fq = l >> 4;
  #pragma unroll
  for (int mi = 0; mi < 4; ++mi) {
    #pragma unroll
    for (int ni = 0; ni < 2; ++ni) {
      int col = n0 + wc * 32 + 16 * ni + fr;
      float bv = bias[col];
      #pragma unroll
      for (int r = 0; r < 4; ++r) {
        int row = m0 + wr * 64 + 16 * mi + fq * 4 + r;
        if (row < M) {
          float val = acc[mi][ni][r] + bv;
          if (OSPLIT) {
            u16 hh, ll; split_bf16(val, hh, ll);
            Chi[(size_t)row * Nc + col] = hh;
            if (!vtile) Clo[(size_t)row * Nc + col] = ll;
          } else {
            Cc[(size_t)row * Nc + col] = val;
          }
        }
      }
    }
  }
}

// ---------------------------------------------------------------------------
// Fused MFMA attention v9 (r15/r17 winner, verbatim): 512 thr, q-tile 128,
// 2 barriers, wave-local tail, Pshift-MFMA rel-k, gM-MFMA buckets.
// LDS 157,696 B.
// ---------------------------------------------------------------------------
__global__ __launch_bounds__(512, 2) void k_attn(
    const u16* __restrict__ qkvhi, const u16* __restrict__ qkvlo,
    const u16* __restrict__ tabKhi, const u16* __restrict__ tabKlo,
    const u16* __restrict__ gM, const u16* __restrict__ gMT,
    const float* __restrict__ tvv, const float* __restrict__ tvh,
    u16* __restrict__ ohi, u16* __restrict__ olo) {
  __shared__ __align__(16) unsigned char LDS[157696];
  unsigned char* Akhi = LDS;
  unsigned char* Aklo = LDS + 34816;
  unsigned char* VhM  = LDS + 69632;
  unsigned char* TvT  = LDS + 112640;
  unsigned char* PvB  = LDS + 120832;
  float* BvBh = (float*)(LDS + 120832);      // [128] stride 34 f32
  unsigned char* MTl  = LDS + 141312;        // [224][32] bf16 swz (S phase)
  unsigned char* Wb   = LDS + 141312;        // post-B2
  unsigned char* Pm   = LDS;

  int bh = blockIdx.x, b = bh / HH, h = bh % HH, qt = blockIdx.y;
  int t = threadIdx.x, w = t >> 6, l = t & 63;
  int fr = l & 15, fq = l >> 4;
  int q0 = 128 * qt;
  const size_t qbase = (size_t)(b * NN) * C3;

  int kr = l >> 3;
  int chunk = ((l & 7) ^ (kr & 7)) * 8;
  for (int i = w; i < 34; i += 8) {
    int rr = 8 * i + kr;
    const u16 *sh, *sl;
    if (rr < 208) {
      int kk = rr > 196 ? 196 : rr;
      sh = qkvhi + qbase + (size_t)kk * C3 + CC + h * DD + chunk;
      sl = qkvlo + qbase + (size_t)kk * C3 + CC + h * DD + chunk;
    } else {
      int tr = rr - 208;
      sh = tabKhi + tr * 64 + chunk;
      sl = tabKlo + tr * 64 + chunk;
    }
    __builtin_amdgcn_global_load_lds(
        (const __attribute__((address_space(1))) void*)sh,
        (__attribute__((address_space(3))) void*)(Akhi + i * 1024), 16, 0, 0);
    __builtin_amdgcn_global_load_lds(
        (const __attribute__((address_space(1))) void*)sl,
        (__attribute__((address_space(3))) void*)(Aklo + i * 1024), 16, 0, 0);
  }
  for (int i = w; i < 14; i += 8) {
    __builtin_amdgcn_global_load_lds(
        (const __attribute__((address_space(1))) void*)(gM + i * 512 + l * 8),
        (__attribute__((address_space(3))) void*)(VhM + 28672 + i * 1024), 16, 0, 0);
  }
  for (int i = w; i < 14; i += 8) {
    __builtin_amdgcn_global_load_lds(
        (const __attribute__((address_space(1))) void*)(gMT + i * 512 + l * 8),
        (__attribute__((address_space(3))) void*)(MTl + i * 1024), 16, 0, 0);
  }
  for (int idx = t; idx < 1576; idx += 512) {
    int k = idx >> 3, d0v = (idx & 7) * 8;
    size_t off = qbase + (size_t)k * C3 + 2 * CC + h * DD + d0v;
    uint4 vh4 = *(const uint4*)(qkvhi + off);
    u16 eh[8] = {(u16)vh4.x, (u16)(vh4.x >> 16), (u16)vh4.y, (u16)(vh4.y >> 16),
                 (u16)vh4.z, (u16)(vh4.z >> 16), (u16)vh4.w, (u16)(vh4.w >> 16)};
    #pragma unroll
    for (int jj = 0; jj < 8; ++jj) {
      int d = d0v + jj;
      int byte = (d * 224 + k) * 2; byte ^= (((d & 7) ^ ((d >> 3) & 7)) << 4);
      *(u16*)(VhM + byte) = eh[jj];
    }
  }
  for (int idx = t; idx < 64 * 27; idx += 512) {
    int d = idx / 27, k = 197 + idx % 27;
    int byte = (d * 224 + k) * 2; byte ^= (((d & 7) ^ ((d >> 3) & 7)) << 4);
    *(u16*)(VhM + byte) = 0;
  }
  for (int i = t; i < 4096; i += 512) {
    int d = i >> 6, tt = i & 63;
    float vv = 0.f;
    if (tt < 30) vv = tvv[tt * 64 + d];
    else if (tt >= 32 && tt < 62) vv = tvh[(tt - 32) * 64 + d];
    int byte = (d * 64 + tt) * 2; byte ^= (((d & 7) ^ ((d >> 3) & 7)) << 4);
    *(u16*)(TvT + byte) = bf16rn(vv);
  }
  bool active = (q0 + 16 * w) < NN;
  bf16x8 qh[2], ql_[2];
  {
    int qg = q0 + 16 * w + fr; int qc = qg > 196 ? 196 : qg;
    const u16* qr  = qkvhi + qbase + (size_t)qc * C3 + h * DD;
    const u16* qr2 = qkvlo + qbase + (size_t)qc * C3 + h * DD;
    qh[0]  = *(const bf16x8*)(qr + 8 * fq);
    qh[1]  = *(const bf16x8*)(qr + 32 + 8 * fq);
    ql_[0] = *(const bf16x8*)(qr2 + 8 * fq);
    ql_[1] = *(const bf16x8*)(qr2 + 32 + 8 * fq);
  }
  __syncthreads();   // B1

  float ex[13][4];
  float inv[4];
  if (active) {
    f32x4 sacc[17] = {};
    #pragma unroll
    for (int ks = 0; ks < 2; ++ks)
      #pragma unroll
      for (int nf = 0; nf < 17; ++nf) {
        int row = 16 * nf + fr;
        int byte = row * 128 + 64 * ks + 16 * fq; byte ^= (row & 7) << 4;
        bf16x8 kf = *(const bf16x8*)(Akhi + byte);
        bf16x8 lf = *(const bf16x8*)(Aklo + byte);
        sacc[nf] = __builtin_amdgcn_mfma_f32_16x16x32_bf16(qh[ks],  kf, sacc[nf], 0, 0, 0);
        sacc[nf] = __builtin_amdgcn_mfma_f32_16x16x32_bf16(ql_[ks], kf, sacc[nf], 0, 0, 0);
        sacc[nf] = __builtin_amdgcn_mfma_f32_16x16x32_bf16(qh[ks],  lf, sacc[nf], 0, 0, 0);
      }
    #pragma unroll
    for (int nf = 13; nf < 17; ++nf)
      #pragma unroll
      for (int r = 0; r < 4; ++r) {
        int c = 16 * (nf - 13) + fr;
        if (c < 60) {
          int row = 16 * w + 4 * fq + r;
          *(u16*)(PvB + row * 160 + 2 * c) = bf16rn(sacc[nf][r]);
        }
      }
    bf16x8 psf;
    {
      int qrow = 16 * w + fr;
      int qg2 = q0 + qrow; int qc2 = qg2 > 196 ? 196 : qg2;
      const unsigned char* rowb = PvB + qrow * 160;
      u16 tmp[8];
      if (qc2 == 0) {
        u16 v0 = *(const u16*)(rowb);
        u16 h0 = *(const u16*)(rowb + 60);
        #pragma unroll
        for (int j = 0; j < 8; ++j) tmp[j] = (8 * fq + j < 16) ? v0 : h0;
      } else {
        int gq2 = (qc2 - 1) / 14, cq2 = (qc2 - 1) % 14;
        #pragma unroll
        for (int j = 0; j < 8; ++j) {
          int tt2 = 8 * fq + j;
          u16 v = 0;
          if (tt2 < 14)       v = *(const u16*)(rowb + 2 * (tt2 - gq2 + 15));
          else if (tt2 == 14) v = *(const u16*)(rowb);
          else if (tt2 >= 16 && tt2 < 30) v = *(const u16*)(rowb + 60 + 2 * (tt2 - 16 - cq2 + 15));
          else if (tt2 == 30) v = *(const u16*)(rowb + 60);
          tmp[j] = v;
        }
      }
      unsigned p0 = tmp[0] | ((unsigned)tmp[1] << 16);
      unsigned p1 = tmp[2] | ((unsigned)tmp[3] << 16);
      unsigned p2 = tmp[4] | ((unsigned)tmp[5] << 16);
      unsigned p3 = tmp[6] | ((unsigned)tmp[7] << 16);
      uint4 pk = make_uint4(p0, p1, p2, p3);
      psf = *(const bf16x8*)&pk;
    }
    #pragma unroll
    for (int nf = 0; nf < 13; ++nf) {
      int row = 16 * nf + fr;
      int byte = row * 64 + 16 * fq; byte ^= (((row >> 1) & 3) << 4);
      bf16x8 mtf = *(const bf16x8*)(MTl + byte);
      sacc[nf] = __builtin_amdgcn_mfma_f32_16x16x32_bf16(psf, mtf, sacc[nf], 0, 0, 0);
    }
    float mrow[4] = {-1e30f, -1e30f, -1e30f, -1e30f};
    #pragma unroll
    for (int nf = 0; nf < 13; ++nf) {
      int k = 16 * nf + fr;
      bool vk = k < 197;
      #pragma unroll
      for (int r = 0; r < 4; ++r) {
        float s = vk ? sacc[nf][r] * SCALE : -1e30f;
        ex[nf][r] = s;
        mrow[r] = fmaxf(mrow[r], s);
      }
    }
    #pragma unroll
    for (int r = 0; r < 4; ++r)
      #pragma unroll
      for (int mk = 1; mk < 16; mk <<= 1) mrow[r] = fmaxf(mrow[r], __shfl_xor(mrow[r], mk));
    float sum[4] = {0.f, 0.f, 0.f, 0.f};
    #pragma unroll
    for (int nf = 0; nf < 13; ++nf)
      #pragma unroll
      for (int r = 0; r < 4; ++r) {
        ex[nf][r] = __expf(ex[nf][r] - mrow[r]);
        sum[r] += ex[nf][r];
      }
    #pragma unroll
    for (int r = 0; r < 4; ++r) {
      #pragma unroll
      for (int mk = 1; mk < 16; mk <<= 1) sum[r] += __shfl_xor(sum[r], mk);
      inv[r] = 1.f / sum[r];
    }
  }
  __syncthreads();   // B2 (LAST barrier)

  #pragma unroll
  for (int nf = 0; nf < 14; ++nf)
    #pragma unroll
    for (int r = 0; r < 4; ++r) {
      int k = 16 * nf + fr;
      int row = 16 * w + 4 * fq + r;
      float p = 0.f;
      if (active && nf < 13 && k < 197) p = ex[nf][r] * inv[r];
      int byte = row * 448 + 2 * k; byte ^= (((row & 7) ^ ((row >> 3) & 7)) << 4);
      *(u16*)(Pm + byte) = bf16rn(p);
    }

  int prow = 16 * w + fr;
  int pswz = ((prow & 7) ^ ((prow >> 3) & 7)) << 4;
  f32x4 ov[4] = {};
  f32x4 om[2] = {};
  #pragma unroll
  for (int ks = 0; ks < 7; ++ks) {
    int co = 64 * ks + 16 * fq;
    bf16x8 pah = *(const bf16x8*)(Pm + ((prow * 448 + co) ^ pswz));
    #pragma unroll
    for (int nf = 0; nf < 4; ++nf) {
      int vrow = 16 * nf + fr;
      int vswz = ((vrow & 7) ^ ((vrow >> 3) & 7)) << 4;
      bf16x8 v = *(const bf16x8*)(VhM + ((vrow * 448 + co) ^ vswz));
      ov[nf] = __builtin_amdgcn_mfma_f32_16x16x32_bf16(pah, v, ov[nf], 0, 0, 0);
    }
    #pragma unroll
    for (int mf = 0; mf < 2; ++mf) {
      int mr = 64 + 16 * mf + fr;
      int mswz = ((mr & 7) ^ ((mr >> 3) & 7)) << 4;
      bf16x8 mv = *(const bf16x8*)(VhM + ((mr * 448 + co) ^ mswz));
      om[mf] = __builtin_amdgcn_mfma_f32_16x16x32_bf16(pah, mv, om[mf], 0, 0, 0);
    }
  }
  #pragma unroll
  for (int mf = 0; mf < 2; ++mf)
    #pragma unroll
    for (int r = 0; r < 4; ++r)
      BvBh[(16 * w + 4 * fq + r) * 34 + 16 * mf + fr] = om[mf][r];

  {
    int row = 16 * w + (l >> 2);
    int qg = q0 + row;
    int half = (l & 3) >> 1;
    int u0 = (l & 1) * 16;
    const float* bb = &BvBh[row * 34 + 16 * half];
    u16 wv[16];
    if (qg == 0) {
      float s = 0.f;
      #pragma unroll
      for (int a = 0; a < 15; ++a) s += bb[a];
      u16 sv = bf16rn(s);
      #pragma unroll
      for (int j = 0; j < 16; ++j) wv[j] = (u0 + j == 0) ? sv : (u16)0;
    } else if (qg < NN) {
      int m = qg - 1;
      int sel = half ? (m % 14) : (m / 14);
      #pragma unroll
      for (int j = 0; j < 16; ++j) {
        int u = u0 + j;
        float val;
        if (u == 0) val = bb[14];
        else {
          int a = u - 15 + sel;
          val = (a >= 0 && a < 14) ? bb[a] : 0.f;
        }
        wv[j] = bf16rn(val);
      }
    } else {
      #pragma unroll
      for (int j = 0; j < 16; ++j) wv[j] = 0;
    }
    uint4 p0, p1;
    p0.x = wv[0]  | ((unsigned)wv[1]  << 16);
    p0.y = wv[2]  | ((unsigned)wv[3]  << 16);
    p0.z = wv[4]  | ((unsigned)wv[5]  << 16);
    p0.w = wv[6]  | ((unsigned)wv[7]  << 16);
    p1.x = wv[8]  | ((unsigned)wv[9]  << 16);
    p1.y = wv[10] | ((unsigned)wv[11] << 16);
    p1.z = wv[12] | ((unsigned)wv[13] << 16);
    p1.w = wv[14] | ((unsigned)wv[15] << 16);
    int base = row * 128 + (l & 3) * 32;
    int sz = ((row & 7) ^ ((row >> 3) & 7)) << 4;
    *(uint4*)(Wb + (base ^ sz)) = p0;
    *(uint4*)(Wb + ((base + 16) ^ sz)) = p1;
  }

  f32x4 rv[4] = {};
  #pragma unroll
  for (int ks2 = 0; ks2 < 2; ++ks2) {
    int co = 64 * ks2 + 16 * fq;
    bf16x8 wa = *(const bf16x8*)(Wb + ((prow * 128 + co) ^ pswz));
    #pragma unroll
    for (int nf = 0; nf < 4; ++nf) {
      int vrow = 16 * nf + fr;
      int vswz = ((vrow & 7) ^ ((vrow >> 3) & 7)) << 4;
      bf16x8 tv = *(const bf16x8*)(TvT + ((vrow * 128 + co) ^ vswz));
      rv[nf] = __builtin_amdgcn_mfma_f32_16x16x32_bf16(wa, tv, rv[nf], 0, 0, 0);
    }
  }

  #pragma unroll
  for (int r = 0; r < 4; ++r) {
    int qrl = 16 * w + 4 * fq + r;
    int qg = q0 + qrl;
    if (qg >= NN) continue;
    size_t ob = (size_t)(b * NN + qg) * CC + h * DD;
    #pragma unroll
    for (int nf = 0; nf < 4; ++nf) {
      int d = 16 * nf + fr;
      float o = ov[nf][r] + rv[nf][r];
      u16 hh, ll;
      split_bf16(o, hh, ll);
      ohi[ob + d] = hh; olo[ob + d] = ll;
    }
  }
}

// ---------------------------------------------------------------------------
// Workspace (u16 units, ~135.7 MB):
//   qkvhi 24,207,360 | qkvlo 24,207,360 | xhi/xlo 2x8,069,120 (reused ohi/olo)
//   weffhi/lo 2x1,228,800 | wphi/lo 2x409,600 | tabKhi/lo 2x4,096
//   gM 7,168 | gMT 7,168
// ---------------------------------------------------------------------------
extern "C" void kernel_launch(void* const* d_in, const int* in_sizes, int n_in,
                              void* d_out, int out_size, void* d_ws, size_t ws_size,
                              hipStream_t stream) {
  (void)in_sizes; (void)n_in; (void)out_size; (void)ws_size;
  const float* x     = (const float*)d_in[0];
  const float* w_qkv = (const float*)d_in[1];
  const float* b_qkv = (const float*)d_in[2];
  const float* la    = (const float*)d_in[3];
  const float* lb    = (const float*)d_in[4];
  const float* tkv   = (const float*)d_in[5];
  const float* tkh   = (const float*)d_in[6];
  const float* tvv   = (const float*)d_in[7];
  const float* tvh   = (const float*)d_in[8];
  const float* wp    = (const float*)d_in[9];
  const float* b_p   = (const float*)d_in[10];

  u16* qkvhi  = (u16*)d_ws;
  u16* qkvlo  = qkvhi + (size_t)24207360;
  u16* xhi    = qkvlo + (size_t)24207360;
  u16* xlo    = xhi + (size_t)8069120;
  u16* ohi    = xhi;                       // alias (x splits dead after gemm1)
  u16* olo    = xlo;
  u16* weffhi = xlo + (size_t)8069120;
  u16* wefflo = weffhi + (size_t)1228800;
  u16* wphi   = wefflo + (size_t)1228800;
  u16* wplo   = wphi + (size_t)409600;
  u16* tabKhi = wplo + (size_t)409600;
  u16* tabKlo = tabKhi + (size_t)4096;
  u16* gM     = tabKlo + (size_t)4096;
  u16* gMT    = gM + (size_t)7168;

  // fused prep: x-split | weff | wproj | tables+gM+gMT (all concurrent)
  k_prep_all<<<14281, 256, 0, stream>>>(x, xhi, xlo,
                                        w_qkv, la, lb, weffhi, wefflo,
                                        wp, wphi, wplo,
                                        tkv, tkh, tabKhi, tabKlo, gM, gMT);

  // qkv = x @ weff^T + b_qkv -> split bf16 output (V tiles: 2-pass, hi-only)
  int nwg1 = ((MTOT + 127) / 128) * (C3 / 128);   // 99*15 = 1485
  k_gemm_mfma<1><<<nwg1, 512, 0, stream>>>(xhi, xlo, weffhi, wefflo, b_qkv,
                                           nullptr, qkvhi, qkvlo, MTOT, C3, C3 / 128, 10);

  // fused attention -> ohi/olo split
  k_attn<<<dim3(BB * HH, 2), 512, 0, stream>>>(qkvhi, qkvlo, tabKhi, tabKlo, gM, gMT,
                                               tvv, tvh, ohi, olo);

  // out = o @ perm3(w_proj)^T + b_proj
  int nwg2 = ((MTOT + 127) / 128) * (CC / 128);   // 99*5 = 495
  k_gemm_mfma<0><<<nwg2, 512, 0, stream>>>(ohi, olo, wphi, wplo, b_p,
                                           (float*)d_out, nullptr, nullptr, MTOT, CC, CC / 128, 999);
}

// Round 19
// 269.690 us; speedup vs baseline: 1.0633x; 1.0117x over previous
//
#include <hip/hip_runtime.h>
#include <math.h>

#define BB 64
#define NN 197
#define HH 10
#define DD 64
#define CC 640
#define C3 1920
#define LR 64
#define MTOT (BB*NN)          // 12608
#define SCALE 0.125f

typedef unsigned short u16;
typedef unsigned long long u64;
typedef __bf16 bf16x8 __attribute__((ext_vector_type(8)));
typedef float f32x4 __attribute__((ext_vector_type(4)));

__device__ __forceinline__ void split_bf16(float f, u16& hi, u16& lo) {
  unsigned u = __float_as_uint(f);
  unsigned r = u + 0x7FFF + ((u >> 16) & 1);
  u16 hb = (u16)(r >> 16);
  float fh = __uint_as_float((unsigned)hb << 16);
  float dl = f - fh;
  unsigned u2 = __float_as_uint(dl);
  unsigned r2 = u2 + 0x7FFF + ((u2 >> 16) & 1);
  hi = hb; lo = (u16)(r2 >> 16);
}

__device__ __forceinline__ u16 bf16rn(float f) {
  unsigned u = __float_as_uint(f);
  return (u16)((u + 0x7FFF + ((u >> 16) & 1)) >> 16);
}
__device__ __forceinline__ float bf16tof(u16 v) {
  return __uint_as_float((unsigned)v << 16);
}

__device__ __forceinline__ int perm640(int i) {
  return (i < 214) ? 3 * i : (i < 427 ? 3 * (i - 214) + 1 : 3 * (i - 427) + 2);
}

// ---------------------------------------------------------------------------
// k_prep_all: fused independent prep (block-range dispatch, all concurrent):
//   [0, 7880):       x -> xhi/xlo split
//   [7880, 12680):   w_eff = perm3(w_qkv + (la@lb)^T) -> hi/lo
//   [12680, 14280):  w_proj perm640 -> hi/lo
//   14280:           tabK hi/lo + gM + gMT
// ---------------------------------------------------------------------------
__global__ __launch_bounds__(256) void k_prep_all(
    const float* __restrict__ x, u16* __restrict__ xhi, u16* __restrict__ xlo,
    const float* __restrict__ w_qkv, const float* __restrict__ la,
    const float* __restrict__ lb, u16* __restrict__ weffhi, u16* __restrict__ wefflo,
    const float* __restrict__ wp, u16* __restrict__ wphi, u16* __restrict__ wplo,
    const float* __restrict__ tkv, const float* __restrict__ tkh,
    u16* __restrict__ thi, u16* __restrict__ tlo,
    u16* __restrict__ gM, u16* __restrict__ gMT) {
  int bid = blockIdx.x;
  if (bid < 7880) {
    int i = bid * 256 + threadIdx.x;
    if (i >= (MTOT * CC) / 4) return;
    float4 v = ((const float4*)x)[i];
    float f[4] = {v.x, v.y, v.z, v.w};
    ushort4 H, L;
    u16 hh, ll;
    split_bf16(f[0], hh, ll); H.x = hh; L.x = ll;
    split_bf16(f[1], hh, ll); H.y = hh; L.y = ll;
    split_bf16(f[2], hh, ll); H.z = hh; L.z = ll;
    split_bf16(f[3], hh, ll); H.w = hh; L.w = ll;
    ((ushort4*)xhi)[i] = H;
    ((ushort4*)xlo)[i] = L;
  } else if (bid < 12680) {
    int idx = (bid - 7880) * 256 + threadIdx.x;   // covers 1920*640
    int i = idx / CC, j = idx % CC;
    int src = 3 * (i % CC) + (i / CC);
    float acc = w_qkv[(size_t)src * CC + j];
    const float* laj = la + (size_t)j * LR;
    const float* lbs = lb + src;
    #pragma unroll 8
    for (int r = 0; r < LR; ++r) acc = fmaf(laj[r], lbs[(size_t)r * C3], acc);
    u16 h, l; split_bf16(acc, h, l);
    weffhi[idx] = h; wefflo[idx] = l;
  } else if (bid < 14280) {
    int idx = (bid - 12680) * 256 + threadIdx.x;  // covers 640*640
    int i = idx / CC, j = idx % CC;
    float v = wp[(size_t)perm640(i) * CC + j];
    u16 h, l; split_bf16(v, h, l);
    wphi[idx] = h; wplo[idx] = l;
  } else {
    for (int idx = threadIdx.x; idx < 4096; idx += 256) {
      int row = idx >> 6, d = idx & 63;
      float v = row < 30 ? tkv[row * 64 + d] : (row < 60 ? tkh[(row - 30) * 64 + d] : 0.f);
      u16 hh, ll; split_bf16(v, hh, ll);
      thi[idx] = hh; tlo[idx] = ll;
    }
    for (int j = threadIdx.x; j < 7168; j += 256) {
      int b = 2 * j;
      u16 v = 0;
      int r0 = b / 448;
      for (int dr = -1; dr <= 1; ++dr) {
        int row = r0 + dr;
        if (row < 0 || row >= 32) continue;
        int g = (row & 7) ^ ((row >> 3) & 7);
        int off = (b ^ (g << 4)) - row * 448;
        if (off >= 0 && off < 448) {
          int k = off >> 1;
          if (k < 197) {
            int a1 = (k == 0) ? 14 : (k - 1) / 14;
            int a2 = (k == 0) ? 14 : (k - 1) % 14;
            if (row < 16) { if (row == a1) v = 0x3F80; }
            else          { if (row - 16 == a2) v = 0x3F80; }
          }
          break;
        }
      }
      gM[j] = v;
    }
    for (int j = threadIdx.x; j < 7168; j += 256) {
      int b = 2 * j;
      int row = b >> 6;
      int off = (b & 63) ^ (((row >> 1) & 3) << 4);
      int tcol = off >> 1;
      u16 v = 0;
      if (row < 197) {
        int a1 = (row == 0) ? 14 : (row - 1) / 14;
        int a2 = (row == 0) ? 14 : (row - 1) % 14;
        if (tcol < 16) { if (tcol == a1) v = 0x3F80; }
        else           { if (tcol - 16 == a2) v = 0x3F80; }
      }
      gMT[j] = v;
    }
  }
}

// ---------------------------------------------------------------------------
// Split-bf16 MFMA GEMM: 8 waves, 64x32 sub-tile/wave, LDS XOR-swizzle,
// n-inner 1D grid + bijective XCD remap. V-tiles (nt >= VNT): 2-pass, hi-only.
// ---------------------------------------------------------------------------
template<int OSPLIT>
__global__ __launch_bounds__(512, 4) void k_gemm_mfma(
    const u16* __restrict__ Ahi, const u16* __restrict__ Alo,
    const u16* __restrict__ Bhi, const u16* __restrict__ Blo,
    const float* __restrict__ bias, float* __restrict__ Cc,
    u16* __restrict__ Chi, u16* __restrict__ Clo,
    int M, int Nc, int NT, int VNT) {
  __shared__ u16 AsH[128][64];
  __shared__ u16 AsL[128][64];
  __shared__ u16 BsH[128][64];
  __shared__ u16 BsL[128][64];
  int t = threadIdx.x, w = t >> 6, l = t & 63;

  int nwg = gridDim.x, bid = blockIdx.x;
  int q8 = nwg >> 3, r8 = nwg & 7;
  int xcd = bid & 7, j8 = bid >> 3;
  int wgid = (xcd < r8 ? xcd * (q8 + 1) : r8 * (q8 + 1) + (xcd - r8) * q8) + j8;
  int mt = wgid / NT, nt = wgid - mt * NT;
  int m0 = mt * 128, n0 = nt * 128;
  bool vtile = (nt >= VNT);

  int wr = w & 1, wc = w >> 1;
  f32x4 acc[4][2] = {};
  int srow = l >> 3;
  int scol = ((l & 7) ^ srow) * 8;

  for (int k0 = 0; k0 < 640; k0 += 64) {
    for (int i = w; i < 16; i += 8) {
      int row = 8 * i + srow;
      int ga = m0 + row; if (ga >= M) ga = M - 1;
      size_t offA = (size_t)ga * 640 + k0 + scol;
      size_t offB = (size_t)(n0 + row) * 640 + k0 + scol;
      __builtin_amdgcn_global_load_lds(
          (const __attribute__((address_space(1))) void*)(Ahi + offA),
          (__attribute__((address_space(3))) void*)(&AsH[8 * i][0]), 16, 0, 0);
      __builtin_amdgcn_global_load_lds(
          (const __attribute__((address_space(1))) void*)(Alo + offA),
          (__attribute__((address_space(3))) void*)(&AsL[8 * i][0]), 16, 0, 0);
      __builtin_amdgcn_global_load_lds(
          (const __attribute__((address_space(1))) void*)(Bhi + offB),
          (__attribute__((address_space(3))) void*)(&BsH[8 * i][0]), 16, 0, 0);
      __builtin_amdgcn_global_load_lds(
          (const __attribute__((address_space(1))) void*)(Blo + offB),
          (__attribute__((address_space(3))) void*)(&BsL[8 * i][0]), 16, 0, 0);
    }
    __syncthreads();
    int fr = l & 15, fq = l >> 4;
    const unsigned char* pAH = (const unsigned char*)&AsH[0][0];
    const unsigned char* pAL = (const unsigned char*)&AsL[0][0];
    const unsigned char* pBH = (const unsigned char*)&BsH[0][0];
    const unsigned char* pBL = (const unsigned char*)&BsL[0][0];
    int fsw = (fr & 7) << 4;
    #pragma unroll
    for (int ks = 0; ks < 2; ++ks) {
      int cbyte = (ks * 64 + fq * 16) ^ fsw;
      bf16x8 ah[4], al[4], bh[2], bl[2];
      #pragma unroll
      for (int mi = 0; mi < 4; ++mi) {
        int ra = (wr * 64 + 16 * mi + fr) * 128 + cbyte;
        ah[mi] = *(const bf16x8*)(pAH + ra);
        al[mi] = *(const bf16x8*)(pAL + ra);
      }
      #pragma unroll
      for (int ni = 0; ni < 2; ++ni) {
        int rb = (wc * 32 + 16 * ni + fr) * 128 + cbyte;
        bh[ni] = *(const bf16x8*)(pBH + rb);
        bl[ni] = *(const bf16x8*)(pBL + rb);
      }
      #pragma unroll
      for (int mi = 0; mi < 4; ++mi)
        #pragma unroll
        for (int ni = 0; ni < 2; ++ni) {
          acc[mi][ni] = __builtin_amdgcn_mfma_f32_16x16x32_bf16(ah[mi], bh[ni], acc[mi][ni], 0, 0, 0);
          acc[mi][ni] = __builtin_amdgcn_mfma_f32_16x16x32_bf16(al[mi], bh[ni], acc[mi][ni], 0, 0, 0);
          if (!vtile)
            acc[mi][ni] = __builtin_amdgcn_mfma_f32_16x16x32_bf16(ah[mi], bl[ni], acc[mi][ni], 0, 0, 0);
        }
    }
    __syncthreads();
  }

  int fr = l & 15, fq = l >> 4;
  #pragma unroll
  for (int mi = 0; mi < 4; ++mi) {
    #pragma unroll
    for (int ni = 0; ni < 2; ++ni) {
      int col = n0 + wc * 32 + 16 * ni + fr;
      float bv = bias[col];
      #pragma unroll
      for (int r = 0; r < 4; ++r) {
        int row = m0 + wr * 64 + 16 * mi + fq * 4 + r;
        if (row < M) {
          float val = acc[mi][ni][r] + bv;
          if (OSPLIT) {
            u16 hh, ll; split_bf16(val, hh, ll);
            Chi[(size_t)row * Nc + col] = hh;
            if (!vtile) Clo[(size_t)row * Nc + col] = ll;
          } else {
            Cc[(size_t)row * Nc + col] = val;
          }
        }
      }
    }
  }
}

// ---------------------------------------------------------------------------
// Fused MFMA attention v9b: r15/r17 structure; V^T staging restructured to
// k-quad granularity: item = (k-quad, d-oct) -> 4 uint4 loads, register
// transpose, 8 ds_write_b64 (4 consecutive k = 8B, alignment kept under x16
// XOR). 448 items, single pass, pad fused (k>=197 -> 0). LDS staging write
// instrs ~14.3k -> 3.6k per block. Everything else unchanged.
// ---------------------------------------------------------------------------
__global__ __launch_bounds__(512, 2) void k_attn(
    const u16* __restrict__ qkvhi, const u16* __restrict__ qkvlo,
    const u16* __restrict__ tabKhi, const u16* __restrict__ tabKlo,
    const u16* __restrict__ gM, const u16* __restrict__ gMT,
    const float* __restrict__ tvv, const float* __restrict__ tvh,
    u16* __restrict__ ohi, u16* __restrict__ olo) {
  __shared__ __align__(16) unsigned char LDS[157696];
  unsigned char* Akhi = LDS;
  unsigned char* Aklo = LDS + 34816;
  unsigned char* VhM  = LDS + 69632;
  unsigned char* TvT  = LDS + 112640;
  unsigned char* PvB  = LDS + 120832;
  float* BvBh = (float*)(LDS + 120832);      // [128] stride 34 f32
  unsigned char* MTl  = LDS + 141312;        // [224][32] bf16 swz (S phase)
  unsigned char* Wb   = LDS + 141312;        // post-B2
  unsigned char* Pm   = LDS;

  int bh = blockIdx.x, b = bh / HH, h = bh % HH, qt = blockIdx.y;
  int t = threadIdx.x, w = t >> 6, l = t & 63;
  int fr = l & 15, fq = l >> 4;
  int q0 = 128 * qt;
  const size_t qbase = (size_t)(b * NN) * C3;

  int kr = l >> 3;
  int chunk = ((l & 7) ^ (kr & 7)) * 8;
  for (int i = w; i < 34; i += 8) {
    int rr = 8 * i + kr;
    const u16 *sh, *sl;
    if (rr < 208) {
      int kk = rr > 196 ? 196 : rr;
      sh = qkvhi + qbase + (size_t)kk * C3 + CC + h * DD + chunk;
      sl = qkvlo + qbase + (size_t)kk * C3 + CC + h * DD + chunk;
    } else {
      int tr = rr - 208;
      sh = tabKhi + tr * 64 + chunk;
      sl = tabKlo + tr * 64 + chunk;
    }
    __builtin_amdgcn_global_load_lds(
        (const __attribute__((address_space(1))) void*)sh,
        (__attribute__((address_space(3))) void*)(Akhi + i * 1024), 16, 0, 0);
    __builtin_amdgcn_global_load_lds(
        (const __attribute__((address_space(1))) void*)sl,
        (__attribute__((address_space(3))) void*)(Aklo + i * 1024), 16, 0, 0);
  }
  for (int i = w; i < 14; i += 8) {
    __builtin_amdgcn_global_load_lds(
        (const __attribute__((address_space(1))) void*)(gM + i * 512 + l * 8),
        (__attribute__((address_space(3))) void*)(VhM + 28672 + i * 1024), 16, 0, 0);
  }
  for (int i = w; i < 14; i += 8) {
    __builtin_amdgcn_global_load_lds(
        (const __attribute__((address_space(1))) void*)(gMT + i * 512 + l * 8),
        (__attribute__((address_space(3))) void*)(MTl + i * 1024), 16, 0, 0);
  }
  // ---- V^T staging, k-quad batched: item = (kq 0..55, oct 0..7) ----
  if (t < 448) {
    int kq = t >> 3, d0v = (t & 7) * 8;
    int k0 = kq * 4;
    uint4 rowv[4];
    #pragma unroll
    for (int j = 0; j < 4; ++j) {
      int k = k0 + j;
      if (k < NN) {
        rowv[j] = *(const uint4*)(qkvhi + qbase + (size_t)k * C3 + 2 * CC + h * DD + d0v);
      } else {
        rowv[j] = make_uint4(0, 0, 0, 0);
      }
    }
    #pragma unroll
    for (int dd = 0; dd < 8; ++dd) {
      int word = dd >> 1, sh16 = (dd & 1) * 16;
      const unsigned* r0p = (const unsigned*)&rowv[0];
      const unsigned* r1p = (const unsigned*)&rowv[1];
      const unsigned* r2p = (const unsigned*)&rowv[2];
      const unsigned* r3p = (const unsigned*)&rowv[3];
      u64 e0 = (u16)(r0p[word] >> sh16);
      u64 e1 = (u16)(r1p[word] >> sh16);
      u64 e2 = (u16)(r2p[word] >> sh16);
      u64 e3 = (u16)(r3p[word] >> sh16);
      u64 pk = e0 | (e1 << 16) | (e2 << 32) | (e3 << 48);
      int d = d0v + dd;
      int byte = (d * 224 + k0) * 2; byte ^= (((d & 7) ^ ((d >> 3) & 7)) << 4);
      *(u64*)(VhM + byte) = pk;
    }
  }
  for (int i = t; i < 4096; i += 512) {
    int d = i >> 6, tt = i & 63;
    float vv = 0.f;
    if (tt < 30) vv = tvv[tt * 64 + d];
    else if (tt >= 32 && tt < 62) vv = tvh[(tt - 32) * 64 + d];
    int byte = (d * 64 + tt) * 2; byte ^= (((d & 7) ^ ((d >> 3) & 7)) << 4);
    *(u16*)(TvT + byte) = bf16rn(vv);
  }
  bool active = (q0 + 16 * w) < NN;
  bf16x8 qh[2], ql_[2];
  {
    int qg = q0 + 16 * w + fr; int qc = qg > 196 ? 196 : qg;
    const u16* qr  = qkvhi + qbase + (size_t)qc * C3 + h * DD;
    const u16* qr2 = qkvlo + qbase + (size_t)qc * C3 + h * DD;
    qh[0]  = *(const bf16x8*)(qr + 8 * fq);
    qh[1]  = *(const bf16x8*)(qr + 32 + 8 * fq);
    ql_[0] = *(const bf16x8*)(qr2 + 8 * fq);
    ql_[1] = *(const bf16x8*)(qr2 + 32 + 8 * fq);
  }
  __syncthreads();   // B1

  float ex[13][4];
  float inv[4];
  if (active) {
    f32x4 sacc[17] = {};
    #pragma unroll
    for (int ks = 0; ks < 2; ++ks)
      #pragma unroll
      for (int nf = 0; nf < 17; ++nf) {
        int row = 16 * nf + fr;
        int byte = row * 128 + 64 * ks + 16 * fq; byte ^= (row & 7) << 4;
        bf16x8 kf = *(const bf16x8*)(Akhi + byte);
        bf16x8 lf = *(const bf16x8*)(Aklo + byte);
        sacc[nf] = __builtin_amdgcn_mfma_f32_16x16x32_bf16(qh[ks],  kf, sacc[nf], 0, 0, 0);
        sacc[nf] = __builtin_amdgcn_mfma_f32_16x16x32_bf16(ql_[ks], kf, sacc[nf], 0, 0, 0);
        sacc[nf] = __builtin_amdgcn_mfma_f32_16x16x32_bf16(qh[ks],  lf, sacc[nf], 0, 0, 0);
      }
    #pragma unroll
    for (int nf = 13; nf < 17; ++nf)
      #pragma unroll
      for (int r = 0; r < 4; ++r) {
        int c = 16 * (nf - 13) + fr;
        if (c < 60) {
          int row = 16 * w + 4 * fq + r;
          *(u16*)(PvB + row * 160 + 2 * c) = bf16rn(sacc[nf][r]);
        }
      }
    bf16x8 psf;
    {
      int qrow = 16 * w + fr;
      int qg2 = q0 + qrow; int qc2 = qg2 > 196 ? 196 : qg2;
      const unsigned char* rowb = PvB + qrow * 160;
      u16 tmp[8];
      if (qc2 == 0) {
        u16 v0 = *(const u16*)(rowb);
        u16 h0 = *(const u16*)(rowb + 60);
        #pragma unroll
        for (int j = 0; j < 8; ++j) tmp[j] = (8 * fq + j < 16) ? v0 : h0;
      } else {
        int gq2 = (qc2 - 1) / 14, cq2 = (qc2 - 1) % 14;
        #pragma unroll
        for (int j = 0; j < 8; ++j) {
          int tt2 = 8 * fq + j;
          u16 v = 0;
          if (tt2 < 14)       v = *(const u16*)(rowb + 2 * (tt2 - gq2 + 15));
          else if (tt2 == 14) v = *(const u16*)(rowb);
          else if (tt2 >= 16 && tt2 < 30) v = *(const u16*)(rowb + 60 + 2 * (tt2 - 16 - cq2 + 15));
          else if (tt2 == 30) v = *(const u16*)(rowb + 60);
          tmp[j] = v;
        }
      }
      unsigned p0 = tmp[0] | ((unsigned)tmp[1] << 16);
      unsigned p1 = tmp[2] | ((unsigned)tmp[3] << 16);
      unsigned p2 = tmp[4] | ((unsigned)tmp[5] << 16);
      unsigned p3 = tmp[6] | ((unsigned)tmp[7] << 16);
      uint4 pk = make_uint4(p0, p1, p2, p3);
      psf = *(const bf16x8*)&pk;
    }
    #pragma unroll
    for (int nf = 0; nf < 13; ++nf) {
      int row = 16 * nf + fr;
      int byte = row * 64 + 16 * fq; byte ^= (((row >> 1) & 3) << 4);
      bf16x8 mtf = *(const bf16x8*)(MTl + byte);
      sacc[nf] = __builtin_amdgcn_mfma_f32_16x16x32_bf16(psf, mtf, sacc[nf], 0, 0, 0);
    }
    float mrow[4] = {-1e30f, -1e30f, -1e30f, -1e30f};
    #pragma unroll
    for (int nf = 0; nf < 13; ++nf) {
      int k = 16 * nf + fr;
      bool vk = k < 197;
      #pragma unroll
      for (int r = 0; r < 4; ++r) {
        float s = vk ? sacc[nf][r] * SCALE : -1e30f;
        ex[nf][r] = s;
        mrow[r] = fmaxf(mrow[r], s);
      }
    }
    #pragma unroll
    for (int r = 0; r < 4; ++r)
      #pragma unroll
      for (int mk = 1; mk < 16; mk <<= 1) mrow[r] = fmaxf(mrow[r], __shfl_xor(mrow[r], mk));
    float sum[4] = {0.f, 0.f, 0.f, 0.f};
    #pragma unroll
    for (int nf = 0; nf < 13; ++nf)
      #pragma unroll
      for (int r = 0; r < 4; ++r) {
        ex[nf][r] = __expf(ex[nf][r] - mrow[r]);
        sum[r] += ex[nf][r];
      }
    #pragma unroll
    for (int r = 0; r < 4; ++r) {
      #pragma unroll
      for (int mk = 1; mk < 16; mk <<= 1) sum[r] += __shfl_xor(sum[r], mk);
      inv[r] = 1.f / sum[r];
    }
  }
  __syncthreads();   // B2 (LAST barrier)

  #pragma unroll
  for (int nf = 0; nf < 14; ++nf)
    #pragma unroll
    for (int r = 0; r < 4; ++r) {
      int k = 16 * nf + fr;
      int row = 16 * w + 4 * fq + r;
      float p = 0.f;
      if (active && nf < 13 && k < 197) p = ex[nf][r] * inv[r];
      int byte = row * 448 + 2 * k; byte ^= (((row & 7) ^ ((row >> 3) & 7)) << 4);
      *(u16*)(Pm + byte) = bf16rn(p);
    }

  int prow = 16 * w + fr;
  int pswz = ((prow & 7) ^ ((prow >> 3) & 7)) << 4;
  f32x4 ov[4] = {};
  f32x4 om[2] = {};
  #pragma unroll
  for (int ks = 0; ks < 7; ++ks) {
    int co = 64 * ks + 16 * fq;
    bf16x8 pah = *(const bf16x8*)(Pm + ((prow * 448 + co) ^ pswz));
    #pragma unroll
    for (int nf = 0; nf < 4; ++nf) {
      int vrow = 16 * nf + fr;
      int vswz = ((vrow & 7) ^ ((vrow >> 3) & 7)) << 4;
      bf16x8 v = *(const bf16x8*)(VhM + ((vrow * 448 + co) ^ vswz));
      ov[nf] = __builtin_amdgcn_mfma_f32_16x16x32_bf16(pah, v, ov[nf], 0, 0, 0);
    }
    #pragma unroll
    for (int mf = 0; mf < 2; ++mf) {
      int mr = 64 + 16 * mf + fr;
      int mswz = ((mr & 7) ^ ((mr >> 3) & 7)) << 4;
      bf16x8 mv = *(const bf16x8*)(VhM + ((mr * 448 + co) ^ mswz));
      om[mf] = __builtin_amdgcn_mfma_f32_16x16x32_bf16(pah, mv, om[mf], 0, 0, 0);
    }
  }
  #pragma unroll
  for (int mf = 0; mf < 2; ++mf)
    #pragma unroll
    for (int r = 0; r < 4; ++r)
      BvBh[(16 * w + 4 * fq + r) * 34 + 16 * mf + fr] = om[mf][r];

  {
    int row = 16 * w + (l >> 2);
    int qg = q0 + row;
    int half = (l & 3) >> 1;
    int u0 = (l & 1) * 16;
    const float* bb = &BvBh[row * 34 + 16 * half];
    u16 wv[16];
    if (qg == 0) {
      float s = 0.f;
      #pragma unroll
      for (int a = 0; a < 15; ++a) s += bb[a];
      u16 sv = bf16rn(s);
      #pragma unroll
      for (int j = 0; j < 16; ++j) wv[j] = (u0 + j == 0) ? sv : (u16)0;
    } else if (qg < NN) {
      int m = qg - 1;
      int sel = half ? (m % 14) : (m / 14);
      #pragma unroll
      for (int j = 0; j < 16; ++j) {
        int u = u0 + j;
        float val;
        if (u == 0) val = bb[14];
        else {
          int a = u - 15 + sel;
          val = (a >= 0 && a < 14) ? bb[a] : 0.f;
        }
        wv[j] = bf16rn(val);
      }
    } else {
      #pragma unroll
      for (int j = 0; j < 16; ++j) wv[j] = 0;
    }
    uint4 p0, p1;
    p0.x = wv[0]  | ((unsigned)wv[1]  << 16);
    p0.y = wv[2]  | ((unsigned)wv[3]  << 16);
    p0.z = wv[4]  | ((unsigned)wv[5]  << 16);
    p0.w = wv[6]  | ((unsigned)wv[7]  << 16);
    p1.x = wv[8]  | ((unsigned)wv[9]  << 16);
    p1.y = wv[10] | ((unsigned)wv[11] << 16);
    p1.z = wv[12] | ((unsigned)wv[13] << 16);
    p1.w = wv[14] | ((unsigned)wv[15] << 16);
    int base = row * 128 + (l & 3) * 32;
    int sz = ((row & 7) ^ ((row >> 3) & 7)) << 4;
    *(uint4*)(Wb + (base ^ sz)) = p0;
    *(uint4*)(Wb + ((base + 16) ^ sz)) = p1;
  }

  f32x4 rv[4] = {};
  #pragma unroll
  for (int ks2 = 0; ks2 < 2; ++ks2) {
    int co = 64 * ks2 + 16 * fq;
    bf16x8 wa = *(const bf16x8*)(Wb + ((prow * 128 + co) ^ pswz));
    #pragma unroll
    for (int nf = 0; nf < 4; ++nf) {
      int vrow = 16 * nf + fr;
      int vswz = ((vrow & 7) ^ ((vrow >> 3) & 7)) << 4;
      bf16x8 tv = *(const bf16x8*)(TvT + ((vrow * 128 + co) ^ vswz));
      rv[nf] = __builtin_amdgcn_mfma_f32_16x16x32_bf16(wa, tv, rv[nf], 0, 0, 0);
    }
  }

  #pragma unroll
  for (int r = 0; r < 4; ++r) {
    int qrl = 16 * w + 4 * fq + r;
    int qg = q0 + qrl;
    if (qg >= NN) continue;
    size_t ob = (size_t)(b * NN + qg) * CC + h * DD;
    #pragma unroll
    for (int nf = 0; nf < 4; ++nf) {
      int d = 16 * nf + fr;
      float o = ov[nf][r] + rv[nf][r];
      u16 hh, ll;
      split_bf16(o, hh, ll);
      ohi[ob + d] = hh; olo[ob + d] = ll;
    }
  }
}

// ---------------------------------------------------------------------------
// Workspace (u16 units, ~135.7 MB):
//   qkvhi 24,207,360 | qkvlo 24,207,360 | xhi/xlo 2x8,069,120 (reused ohi/olo)
//   weffhi/lo 2x1,228,800 | wphi/lo 2x409,600 | tabKhi/lo 2x4,096
//   gM 7,168 | gMT 7,168
// ---------------------------------------------------------------------------
extern "C" void kernel_launch(void* const* d_in, const int* in_sizes, int n_in,
                              void* d_out, int out_size, void* d_ws, size_t ws_size,
                              hipStream_t stream) {
  (void)in_sizes; (void)n_in; (void)out_size; (void)ws_size;
  const float* x     = (const float*)d_in[0];
  const float* w_qkv = (const float*)d_in[1];
  const float* b_qkv = (const float*)d_in[2];
  const float* la    = (const float*)d_in[3];
  const float* lb    = (const float*)d_in[4];
  const float* tkv   = (const float*)d_in[5];
  const float* tkh   = (const float*)d_in[6];
  const float* tvv   = (const float*)d_in[7];
  const float* tvh   = (const float*)d_in[8];
  const float* wp    = (const float*)d_in[9];
  const float* b_p   = (const float*)d_in[10];

  u16* qkvhi  = (u16*)d_ws;
  u16* qkvlo  = qkvhi + (size_t)24207360;
  u16* xhi    = qkvlo + (size_t)24207360;
  u16* xlo    = xhi + (size_t)8069120;
  u16* ohi    = xhi;                       // alias (x splits dead after gemm1)
  u16* olo    = xlo;
  u16* weffhi = xlo + (size_t)8069120;
  u16* wefflo = weffhi + (size_t)1228800;
  u16* wphi   = wefflo + (size_t)1228800;
  u16* wplo   = wphi + (size_t)409600;
  u16* tabKhi = wplo + (size_t)409600;
  u16* tabKlo = tabKhi + (size_t)4096;
  u16* gM     = tabKlo + (size_t)4096;
  u16* gMT    = gM + (size_t)7168;

  // fused prep: x-split | weff | wproj | tables+gM+gMT (all concurrent)
  k_prep_all<<<14281, 256, 0, stream>>>(x, xhi, xlo,
                                        w_qkv, la, lb, weffhi, wefflo,
                                        wp, wphi, wplo,
                                        tkv, tkh, tabKhi, tabKlo, gM, gMT);

  // qkv = x @ weff^T + b_qkv -> split bf16 output (V tiles: 2-pass, hi-only)
  int nwg1 = ((MTOT + 127) / 128) * (C3 / 128);   // 99*15 = 1485
  k_gemm_mfma<1><<<nwg1, 512, 0, stream>>>(xhi, xlo, weffhi, wefflo, b_qkv,
                                           nullptr, qkvhi, qkvlo, MTOT, C3, C3 / 128, 10);

  // fused attention -> ohi/olo split
  k_attn<<<dim3(BB * HH, 2), 512, 0, stream>>>(qkvhi, qkvlo, tabKhi, tabKlo, gM, gMT,
                                               tvv, tvh, ohi, olo);

  // out = o @ perm3(w_proj)^T + b_proj
  int nwg2 = ((MTOT + 127) / 128) * (CC / 128);   // 99*5 = 495
  k_gemm_mfma<0><<<nwg2, 512, 0, stream>>>(ohi, olo, wphi, wplo, b_p,
                                           (float*)d_out, nullptr, nullptr, MTOT, CC, CC / 128, 999);
}

// Round 20
// 263.468 us; speedup vs baseline: 1.0884x; 1.0236x over previous
//
#include <hip/hip_runtime.h>
#include <math.h>

#define BB 64
#define NN 197
#define HH 10
#define DD 64
#define CC 640
#define C3 1920
#define LR 64
#define MTOT (BB*NN)          // 12608
#define SCALE 0.125f

typedef unsigned short u16;
typedef unsigned long long u64;
typedef __bf16 bf16x8 __attribute__((ext_vector_type(8)));
typedef float f32x4 __attribute__((ext_vector_type(4)));

__device__ __forceinline__ void split_bf16(float f, u16& hi, u16& lo) {
  unsigned u = __float_as_uint(f);
  unsigned r = u + 0x7FFF + ((u >> 16) & 1);
  u16 hb = (u16)(r >> 16);
  float fh = __uint_as_float((unsigned)hb << 16);
  float dl = f - fh;
  unsigned u2 = __float_as_uint(dl);
  unsigned r2 = u2 + 0x7FFF + ((u2 >> 16) & 1);
  hi = hb; lo = (u16)(r2 >> 16);
}

__device__ __forceinline__ u16 bf16rn(float f) {
  unsigned u = __float_as_uint(f);
  return (u16)((u + 0x7FFF + ((u >> 16) & 1)) >> 16);
}
__device__ __forceinline__ float bf16tof(u16 v) {
  return __uint_as_float((unsigned)v << 16);
}

__device__ __forceinline__ int perm640(int i) {
  return (i < 214) ? 3 * i : (i < 427 ? 3 * (i - 214) + 1 : 3 * (i - 427) + 2);
}

// ---------------------------------------------------------------------------
// k_prep_all: fused independent prep (block-range dispatch, all concurrent):
//   [0, 7880):       x -> xhi/xlo split
//   [7880, 12680):   w_eff = perm3(w_qkv + (la@lb)^T) -> hi/lo
//   [12680, 14280):  w_proj perm640 -> hi/lo
//   14280:           tabK hi/lo + gM + gMT
// ---------------------------------------------------------------------------
__global__ __launch_bounds__(256) void k_prep_all(
    const float* __restrict__ x, u16* __restrict__ xhi, u16* __restrict__ xlo,
    const float* __restrict__ w_qkv, const float* __restrict__ la,
    const float* __restrict__ lb, u16* __restrict__ weffhi, u16* __restrict__ wefflo,
    const float* __restrict__ wp, u16* __restrict__ wphi, u16* __restrict__ wplo,
    const float* __restrict__ tkv, const float* __restrict__ tkh,
    u16* __restrict__ thi, u16* __restrict__ tlo,
    u16* __restrict__ gM, u16* __restrict__ gMT) {
  int bid = blockIdx.x;
  if (bid < 7880) {
    int i = bid * 256 + threadIdx.x;
    if (i >= (MTOT * CC) / 4) return;
    float4 v = ((const float4*)x)[i];
    float f[4] = {v.x, v.y, v.z, v.w};
    ushort4 H, L;
    u16 hh, ll;
    split_bf16(f[0], hh, ll); H.x = hh; L.x = ll;
    split_bf16(f[1], hh, ll); H.y = hh; L.y = ll;
    split_bf16(f[2], hh, ll); H.z = hh; L.z = ll;
    split_bf16(f[3], hh, ll); H.w = hh; L.w = ll;
    ((ushort4*)xhi)[i] = H;
    ((ushort4*)xlo)[i] = L;
  } else if (bid < 12680) {
    int idx = (bid - 7880) * 256 + threadIdx.x;   // covers 1920*640
    int i = idx / CC, j = idx % CC;
    int src = 3 * (i % CC) + (i / CC);
    float acc = w_qkv[(size_t)src * CC + j];
    const float* laj = la + (size_t)j * LR;
    const float* lbs = lb + src;
    #pragma unroll 8
    for (int r = 0; r < LR; ++r) acc = fmaf(laj[r], lbs[(size_t)r * C3], acc);
    u16 h, l; split_bf16(acc, h, l);
    weffhi[idx] = h; wefflo[idx] = l;
  } else if (bid < 14280) {
    int idx = (bid - 12680) * 256 + threadIdx.x;  // covers 640*640
    int i = idx / CC, j = idx % CC;
    float v = wp[(size_t)perm640(i) * CC + j];
    u16 h, l; split_bf16(v, h, l);
    wphi[idx] = h; wplo[idx] = l;
  } else {
    for (int idx = threadIdx.x; idx < 4096; idx += 256) {
      int row = idx >> 6, d = idx & 63;
      float v = row < 30 ? tkv[row * 64 + d] : (row < 60 ? tkh[(row - 30) * 64 + d] : 0.f);
      u16 hh, ll; split_bf16(v, hh, ll);
      thi[idx] = hh; tlo[idx] = ll;
    }
    for (int j = threadIdx.x; j < 7168; j += 256) {
      int b = 2 * j;
      u16 v = 0;
      int r0 = b / 448;
      for (int dr = -1; dr <= 1; ++dr) {
        int row = r0 + dr;
        if (row < 0 || row >= 32) continue;
        int g = (row & 7) ^ ((row >> 3) & 7);
        int off = (b ^ (g << 4)) - row * 448;
        if (off >= 0 && off < 448) {
          int k = off >> 1;
          if (k < 197) {
            int a1 = (k == 0) ? 14 : (k - 1) / 14;
            int a2 = (k == 0) ? 14 : (k - 1) % 14;
            if (row < 16) { if (row == a1) v = 0x3F80; }
            else          { if (row - 16 == a2) v = 0x3F80; }
          }
          break;
        }
      }
      gM[j] = v;
    }
    for (int j = threadIdx.x; j < 7168; j += 256) {
      int b = 2 * j;
      int row = b >> 6;
      int off = (b & 63) ^ (((row >> 1) & 3) << 4);
      int tcol = off >> 1;
      u16 v = 0;
      if (row < 197) {
        int a1 = (row == 0) ? 14 : (row - 1) / 14;
        int a2 = (row == 0) ? 14 : (row - 1) % 14;
        if (tcol < 16) { if (tcol == a1) v = 0x3F80; }
        else           { if (tcol - 16 == a2) v = 0x3F80; }
      }
      gMT[j] = v;
    }
  }
}

// ---------------------------------------------------------------------------
// Split-bf16 MFMA GEMM: 8 waves, 64x32 sub-tile/wave, LDS XOR-swizzle,
// n-inner 1D grid + bijective XCD remap. V-tiles (nt >= VNT): 2-pass, hi-only.
// ---------------------------------------------------------------------------
template<int OSPLIT>
__global__ __launch_bounds__(512, 4) void k_gemm_mfma(
    const u16* __restrict__ Ahi, const u16* __restrict__ Alo,
    const u16* __restrict__ Bhi, const u16* __restrict__ Blo,
    const float* __restrict__ bias, float* __restrict__ Cc,
    u16* __restrict__ Chi, u16* __restrict__ Clo,
    int M, int Nc, int NT, int VNT) {
  __shared__ u16 AsH[128][64];
  __shared__ u16 AsL[128][64];
  __shared__ u16 BsH[128][64];
  __shared__ u16 BsL[128][64];
  int t = threadIdx.x, w = t >> 6, l = t & 63;

  int nwg = gridDim.x, bid = blockIdx.x;
  int q8 = nwg >> 3, r8 = nwg & 7;
  int xcd = bid & 7, j8 = bid >> 3;
  int wgid = (xcd < r8 ? xcd * (q8 + 1) : r8 * (q8 + 1) + (xcd - r8) * q8) + j8;
  int mt = wgid / NT, nt = wgid - mt * NT;
  int m0 = mt * 128, n0 = nt * 128;
  bool vtile = (nt >= VNT);

  int wr = w & 1, wc = w >> 1;
  f32x4 acc[4][2] = {};
  int srow = l >> 3;
  int scol = ((l & 7) ^ srow) * 8;

  for (int k0 = 0; k0 < 640; k0 += 64) {
    for (int i = w; i < 16; i += 8) {
      int row = 8 * i + srow;
      int ga = m0 + row; if (ga >= M) ga = M - 1;
      size_t offA = (size_t)ga * 640 + k0 + scol;
      size_t offB = (size_t)(n0 + row) * 640 + k0 + scol;
      __builtin_amdgcn_global_load_lds(
          (const __attribute__((address_space(1))) void*)(Ahi + offA),
          (__attribute__((address_space(3))) void*)(&AsH[8 * i][0]), 16, 0, 0);
      __builtin_amdgcn_global_load_lds(
          (const __attribute__((address_space(1))) void*)(Alo + offA),
          (__attribute__((address_space(3))) void*)(&AsL[8 * i][0]), 16, 0, 0);
      __builtin_amdgcn_global_load_lds(
          (const __attribute__((address_space(1))) void*)(Bhi + offB),
          (__attribute__((address_space(3))) void*)(&BsH[8 * i][0]), 16, 0, 0);
      __builtin_amdgcn_global_load_lds(
          (const __attribute__((address_space(1))) void*)(Blo + offB),
          (__attribute__((address_space(3))) void*)(&BsL[8 * i][0]), 16, 0, 0);
    }
    __syncthreads();
    int fr = l & 15, fq = l >> 4;
    const unsigned char* pAH = (const unsigned char*)&AsH[0][0];
    const unsigned char* pAL = (const unsigned char*)&AsL[0][0];
    const unsigned char* pBH = (const unsigned char*)&BsH[0][0];
    const unsigned char* pBL = (const unsigned char*)&BsL[0][0];
    int fsw = (fr & 7) << 4;
    #pragma unroll
    for (int ks = 0; ks < 2; ++ks) {
      int cbyte = (ks * 64 + fq * 16) ^ fsw;
      bf16x8 ah[4], al[4], bh[2], bl[2];
      #pragma unroll
      for (int mi = 0; mi < 4; ++mi) {
        int ra = (wr * 64 + 16 * mi + fr) * 128 + cbyte;
        ah[mi] = *(const bf16x8*)(pAH + ra);
        al[mi] = *(const bf16x8*)(pAL + ra);
      }
      #pragma unroll
      for (int ni = 0; ni < 2; ++ni) {
        int rb = (wc * 32 + 16 * ni + fr) * 128 + cbyte;
        bh[ni] = *(const bf16x8*)(pBH + rb);
        bl[ni] = *(const bf16x8*)(pBL + rb);
      }
      #pragma unroll
      for (int mi = 0; mi < 4; ++mi)
        #pragma unroll
        for (int ni = 0; ni < 2; ++ni) {
          acc[mi][ni] = __builtin_amdgcn_mfma_f32_16x16x32_bf16(ah[mi], bh[ni], acc[mi][ni], 0, 0, 0);
          acc[mi][ni] = __builtin_amdgcn_mfma_f32_16x16x32_bf16(al[mi], bh[ni], acc[mi][ni], 0, 0, 0);
          if (!vtile)
            acc[mi][ni] = __builtin_amdgcn_mfma_f32_16x16x32_bf16(ah[mi], bl[ni], acc[mi][ni], 0, 0, 0);
        }
    }
    __syncthreads();
  }

  int fr = l & 15, fq = l >> 4;
  #pragma unroll
  for (int mi = 0; mi < 4; ++mi) {
    #pragma unroll
    for (int ni = 0; ni < 2; ++ni) {
      int col = n0 + wc * 32 + 16 * ni + fr;
      float bv = bias[col];
      #pragma unroll
      for (int r = 0; r < 4; ++r) {
        int row = m0 + wr * 64 + 16 * mi + fq * 4 + r;
        if (row < M) {
          float val = acc[mi][ni][r] + bv;
          if (OSPLIT) {
            u16 hh, ll; split_bf16(val, hh, ll);
            Chi[(size_t)row * Nc + col] = hh;
            if (!vtile) Clo[(size_t)row * Nc + col] = ll;
          } else {
            Cc[(size_t)row * Nc + col] = val;
          }
        }
      }
    }
  }
}

// ---------------------------------------------------------------------------
// Fused MFMA attention v9c: r19 structure; grid flattened to 1-D 1280 blocks
// with inverse-XCD chunk mapping (wgid = (bid&7)*160 + bid>>3; 1280%8==0 ->
// bijective). The (bh, qt=0/1) pair (wgid 2m, 2m+1) lands on the SAME XCD
// adjacent in time -> second block's K/V glds hit that XCD's L2 (~200cy vs
// ~900cy HBM) and shared K/V fetched once. Everything else identical to r19.
// ---------------------------------------------------------------------------
__global__ __launch_bounds__(512, 2) void k_attn(
    const u16* __restrict__ qkvhi, const u16* __restrict__ qkvlo,
    const u16* __restrict__ tabKhi, const u16* __restrict__ tabKlo,
    const u16* __restrict__ gM, const u16* __restrict__ gMT,
    const float* __restrict__ tvv, const float* __restrict__ tvh,
    u16* __restrict__ ohi, u16* __restrict__ olo) {
  __shared__ __align__(16) unsigned char LDS[157696];
  unsigned char* Akhi = LDS;
  unsigned char* Aklo = LDS + 34816;
  unsigned char* VhM  = LDS + 69632;
  unsigned char* TvT  = LDS + 112640;
  unsigned char* PvB  = LDS + 120832;
  float* BvBh = (float*)(LDS + 120832);      // [128] stride 34 f32
  unsigned char* MTl  = LDS + 141312;        // [224][32] bf16 swz (S phase)
  unsigned char* Wb   = LDS + 141312;        // post-B2
  unsigned char* Pm   = LDS;

  // 1-D grid, inverse-XCD chunk map: (bh,qt) pair adjacent on same XCD
  int bid = blockIdx.x;
  int wgid = (bid & 7) * 160 + (bid >> 3);   // 1280 = 8 x 160, bijective
  int bh = wgid >> 1, qt = wgid & 1;
  int b = bh / HH, h = bh % HH;
  int t = threadIdx.x, w = t >> 6, l = t & 63;
  int fr = l & 15, fq = l >> 4;
  int q0 = 128 * qt;
  const size_t qbase = (size_t)(b * NN) * C3;

  int kr = l >> 3;
  int chunk = ((l & 7) ^ (kr & 7)) * 8;
  for (int i = w; i < 34; i += 8) {
    int rr = 8 * i + kr;
    const u16 *sh, *sl;
    if (rr < 208) {
      int kk = rr > 196 ? 196 : rr;
      sh = qkvhi + qbase + (size_t)kk * C3 + CC + h * DD + chunk;
      sl = qkvlo + qbase + (size_t)kk * C3 + CC + h * DD + chunk;
    } else {
      int tr = rr - 208;
      sh = tabKhi + tr * 64 + chunk;
      sl = tabKlo + tr * 64 + chunk;
    }
    __builtin_amdgcn_global_load_lds(
        (const __attribute__((address_space(1))) void*)sh,
        (__attribute__((address_space(3))) void*)(Akhi + i * 1024), 16, 0, 0);
    __builtin_amdgcn_global_load_lds(
        (const __attribute__((address_space(1))) void*)sl,
        (__attribute__((address_space(3))) void*)(Aklo + i * 1024), 16, 0, 0);
  }
  for (int i = w; i < 14; i += 8) {
    __builtin_amdgcn_global_load_lds(
        (const __attribute__((address_space(1))) void*)(gM + i * 512 + l * 8),
        (__attribute__((address_space(3))) void*)(VhM + 28672 + i * 1024), 16, 0, 0);
  }
  for (int i = w; i < 14; i += 8) {
    __builtin_amdgcn_global_load_lds(
        (const __attribute__((address_space(1))) void*)(gMT + i * 512 + l * 8),
        (__attribute__((address_space(3))) void*)(MTl + i * 1024), 16, 0, 0);
  }
  // ---- V^T staging, k-quad batched: item = (kq 0..55, oct 0..7) ----
  if (t < 448) {
    int kq = t >> 3, d0v = (t & 7) * 8;
    int k0 = kq * 4;
    uint4 rowv[4];
    #pragma unroll
    for (int j = 0; j < 4; ++j) {
      int k = k0 + j;
      if (k < NN) {
        rowv[j] = *(const uint4*)(qkvhi + qbase + (size_t)k * C3 + 2 * CC + h * DD + d0v);
      } else {
        rowv[j] = make_uint4(0, 0, 0, 0);
      }
    }
    #pragma unroll
    for (int dd = 0; dd < 8; ++dd) {
      int word = dd >> 1, sh16 = (dd & 1) * 16;
      const unsigned* r0p = (const unsigned*)&rowv[0];
      const unsigned* r1p = (const unsigned*)&rowv[1];
      const unsigned* r2p = (const unsigned*)&rowv[2];
      const unsigned* r3p = (const unsigned*)&rowv[3];
      u64 e0 = (u16)(r0p[word] >> sh16);
      u64 e1 = (u16)(r1p[word] >> sh16);
      u64 e2 = (u16)(r2p[word] >> sh16);
      u64 e3 = (u16)(r3p[word] >> sh16);
      u64 pk = e0 | (e1 << 16) | (e2 << 32) | (e3 << 48);
      int d = d0v + dd;
      int byte = (d * 224 + k0) * 2; byte ^= (((d & 7) ^ ((d >> 3) & 7)) << 4);
      *(u64*)(VhM + byte) = pk;
    }
  }
  for (int i = t; i < 4096; i += 512) {
    int d = i >> 6, tt = i & 63;
    float vv = 0.f;
    if (tt < 30) vv = tvv[tt * 64 + d];
    else if (tt >= 32 && tt < 62) vv = tvh[(tt - 32) * 64 + d];
    int byte = (d * 64 + tt) * 2; byte ^= (((d & 7) ^ ((d >> 3) & 7)) << 4);
    *(u16*)(TvT + byte) = bf16rn(vv);
  }
  bool active = (q0 + 16 * w) < NN;
  bf16x8 qh[2], ql_[2];
  {
    int qg = q0 + 16 * w + fr; int qc = qg > 196 ? 196 : qg;
    const u16* qr  = qkvhi + qbase + (size_t)qc * C3 + h * DD;
    const u16* qr2 = qkvlo + qbase + (size_t)qc * C3 + h * DD;
    qh[0]  = *(const bf16x8*)(qr + 8 * fq);
    qh[1]  = *(const bf16x8*)(qr + 32 + 8 * fq);
    ql_[0] = *(const bf16x8*)(qr2 + 8 * fq);
    ql_[1] = *(const bf16x8*)(qr2 + 32 + 8 * fq);
  }
  __syncthreads();   // B1

  float ex[13][4];
  float inv[4];
  if (active) {
    f32x4 sacc[17] = {};
    #pragma unroll
    for (int ks = 0; ks < 2; ++ks)
      #pragma unroll
      for (int nf = 0; nf < 17; ++nf) {
        int row = 16 * nf + fr;
        int byte = row * 128 + 64 * ks + 16 * fq; byte ^= (row & 7) << 4;
        bf16x8 kf = *(const bf16x8*)(Akhi + byte);
        bf16x8 lf = *(const bf16x8*)(Aklo + byte);
        sacc[nf] = __builtin_amdgcn_mfma_f32_16x16x32_bf16(qh[ks],  kf, sacc[nf], 0, 0, 0);
        sacc[nf] = __builtin_amdgcn_mfma_f32_16x16x32_bf16(ql_[ks], kf, sacc[nf], 0, 0, 0);
        sacc[nf] = __builtin_amdgcn_mfma_f32_16x16x32_bf16(qh[ks],  lf, sacc[nf], 0, 0, 0);
      }
    #pragma unroll
    for (int nf = 13; nf < 17; ++nf)
      #pragma unroll
      for (int r = 0; r < 4; ++r) {
        int c = 16 * (nf - 13) + fr;
        if (c < 60) {
          int row = 16 * w + 4 * fq + r;
          *(u16*)(PvB + row * 160 + 2 * c) = bf16rn(sacc[nf][r]);
        }
      }
    bf16x8 psf;
    {
      int qrow = 16 * w + fr;
      int qg2 = q0 + qrow; int qc2 = qg2 > 196 ? 196 : qg2;
      const unsigned char* rowb = PvB + qrow * 160;
      u16 tmp[8];
      if (qc2 == 0) {
        u16 v0 = *(const u16*)(rowb);
        u16 h0 = *(const u16*)(rowb + 60);
        #pragma unroll
        for (int j = 0; j < 8; ++j) tmp[j] = (8 * fq + j < 16) ? v0 : h0;
      } else {
        int gq2 = (qc2 - 1) / 14, cq2 = (qc2 - 1) % 14;
        #pragma unroll
        for (int j = 0; j < 8; ++j) {
          int tt2 = 8 * fq + j;
          u16 v = 0;
          if (tt2 < 14)       v = *(const u16*)(rowb + 2 * (tt2 - gq2 + 15));
          else if (tt2 == 14) v = *(const u16*)(rowb);
          else if (tt2 >= 16 && tt2 < 30) v = *(const u16*)(rowb + 60 + 2 * (tt2 - 16 - cq2 + 15));
          else if (tt2 == 30) v = *(const u16*)(rowb + 60);
          tmp[j] = v;
        }
      }
      unsigned p0 = tmp[0] | ((unsigned)tmp[1] << 16);
      unsigned p1 = tmp[2] | ((unsigned)tmp[3] << 16);
      unsigned p2 = tmp[4] | ((unsigned)tmp[5] << 16);
      unsigned p3 = tmp[6] | ((unsigned)tmp[7] << 16);
      uint4 pk = make_uint4(p0, p1, p2, p3);
      psf = *(const bf16x8*)&pk;
    }
    #pragma unroll
    for (int nf = 0; nf < 13; ++nf) {
      int row = 16 * nf + fr;
      int byte = row * 64 + 16 * fq; byte ^= (((row >> 1) & 3) << 4);
      bf16x8 mtf = *(const bf16x8*)(MTl + byte);
      sacc[nf] = __builtin_amdgcn_mfma_f32_16x16x32_bf16(psf, mtf, sacc[nf], 0, 0, 0);
    }
    float mrow[4] = {-1e30f, -1e30f, -1e30f, -1e30f};
    #pragma unroll
    for (int nf = 0; nf < 13; ++nf) {
      int k = 16 * nf + fr;
      bool vk = k < 197;
      #pragma unroll
      for (int r = 0; r < 4; ++r) {
        float s = vk ? sacc[nf][r] * SCALE : -1e30f;
        ex[nf][r] = s;
        mrow[r] = fmaxf(mrow[r], s);
      }
    }
    #pragma unroll
    for (int r = 0; r < 4; ++r)
      #pragma unroll
      for (int mk = 1; mk < 16; mk <<= 1) mrow[r] = fmaxf(mrow[r], __shfl_xor(mrow[r], mk));
    float sum[4] = {0.f, 0.f, 0.f, 0.f};
    #pragma unroll
    for (int nf = 0; nf < 13; ++nf)
      #pragma unroll
      for (int r = 0; r < 4; ++r) {
        ex[nf][r] = __expf(ex[nf][r] - mrow[r]);
        sum[r] += ex[nf][r];
      }
    #pragma unroll
    for (int r = 0; r < 4; ++r) {
      #pragma unroll
      for (int mk = 1; mk < 16; mk <<= 1) sum[r] += __shfl_xor(sum[r], mk);
      inv[r] = 1.f / sum[r];
    }
  }
  __syncthreads();   // B2 (LAST barrier)

  #pragma unroll
  for (int nf = 0; nf < 14; ++nf)
    #pragma unroll
    for (int r = 0; r < 4; ++r) {
      int k = 16 * nf + fr;
      int row = 16 * w + 4 * fq + r;
      float p = 0.f;
      if (active && nf < 13 && k < 197) p = ex[nf][r] * inv[r];
      int byte = row * 448 + 2 * k; byte ^= (((row & 7) ^ ((row >> 3) & 7)) << 4);
      *(u16*)(Pm + byte) = bf16rn(p);
    }

  int prow = 16 * w + fr;
  int pswz = ((prow & 7) ^ ((prow >> 3) & 7)) << 4;
  f32x4 ov[4] = {};
  f32x4 om[2] = {};
  #pragma unroll
  for (int ks = 0; ks < 7; ++ks) {
    int co = 64 * ks + 16 * fq;
    bf16x8 pah = *(const bf16x8*)(Pm + ((prow * 448 + co) ^ pswz));
    #pragma unroll
    for (int nf = 0; nf < 4; ++nf) {
      int vrow = 16 * nf + fr;
      int vswz = ((vrow & 7) ^ ((vrow >> 3) & 7)) << 4;
      bf16x8 v = *(const bf16x8*)(VhM + ((vrow * 448 + co) ^ vswz));
      ov[nf] = __builtin_amdgcn_mfma_f32_16x16x32_bf16(pah, v, ov[nf], 0, 0, 0);
    }
    #pragma unroll
    for (int mf = 0; mf < 2; ++mf) {
      int mr = 64 + 16 * mf + fr;
      int mswz = ((mr & 7) ^ ((mr >> 3) & 7)) << 4;
      bf16x8 mv = *(const bf16x8*)(VhM + ((mr * 448 + co) ^ mswz));
      om[mf] = __builtin_amdgcn_mfma_f32_16x16x32_bf16(pah, mv, om[mf], 0, 0, 0);
    }
  }
  #pragma unroll
  for (int mf = 0; mf < 2; ++mf)
    #pragma unroll
    for (int r = 0; r < 4; ++r)
      BvBh[(16 * w + 4 * fq + r) * 34 + 16 * mf + fr] = om[mf][r];

  {
    int row = 16 * w + (l >> 2);
    int qg = q0 + row;
    int half = (l & 3) >> 1;
    int u0 = (l & 1) * 16;
    const float* bb = &BvBh[row * 34 + 16 * half];
    u16 wv[16];
    if (qg == 0) {
      float s = 0.f;
      #pragma unroll
      for (int a = 0; a < 15; ++a) s += bb[a];
      u16 sv = bf16rn(s);
      #pragma unroll
      for (int j = 0; j < 16; ++j) wv[j] = (u0 + j == 0) ? sv : (u16)0;
    } else if (qg < NN) {
      int m = qg - 1;
      int sel = half ? (m % 14) : (m / 14);
      #pragma unroll
      for (int j = 0; j < 16; ++j) {
        int u = u0 + j;
        float val;
        if (u == 0) val = bb[14];
        else {
          int a = u - 15 + sel;
          val = (a >= 0 && a < 14) ? bb[a] : 0.f;
        }
        wv[j] = bf16rn(val);
      }
    } else {
      #pragma unroll
      for (int j = 0; j < 16; ++j) wv[j] = 0;
    }
    uint4 p0, p1;
    p0.x = wv[0]  | ((unsigned)wv[1]  << 16);
    p0.y = wv[2]  | ((unsigned)wv[3]  << 16);
    p0.z = wv[4]  | ((unsigned)wv[5]  << 16);
    p0.w = wv[6]  | ((unsigned)wv[7]  << 16);
    p1.x = wv[8]  | ((unsigned)wv[9]  << 16);
    p1.y = wv[10] | ((unsigned)wv[11] << 16);
    p1.z = wv[12] | ((unsigned)wv[13] << 16);
    p1.w = wv[14] | ((unsigned)wv[15] << 16);
    int base = row * 128 + (l & 3) * 32;
    int sz = ((row & 7) ^ ((row >> 3) & 7)) << 4;
    *(uint4*)(Wb + (base ^ sz)) = p0;
    *(uint4*)(Wb + ((base + 16) ^ sz)) = p1;
  }

  f32x4 rv[4] = {};
  #pragma unroll
  for (int ks2 = 0; ks2 < 2; ++ks2) {
    int co = 64 * ks2 + 16 * fq;
    bf16x8 wa = *(const bf16x8*)(Wb + ((prow * 128 + co) ^ pswz));
    #pragma unroll
    for (int nf = 0; nf < 4; ++nf) {
      int vrow = 16 * nf + fr;
      int vswz = ((vrow & 7) ^ ((vrow >> 3) & 7)) << 4;
      bf16x8 tv = *(const bf16x8*)(TvT + ((vrow * 128 + co) ^ vswz));
      rv[nf] = __builtin_amdgcn_mfma_f32_16x16x32_bf16(wa, tv, rv[nf], 0, 0, 0);
    }
  }

  #pragma unroll
  for (int r = 0; r < 4; ++r) {
    int qrl = 16 * w + 4 * fq + r;
    int qg = q0 + qrl;
    if (qg >= NN) continue;
    size_t ob = (size_t)(b * NN + qg) * CC + h * DD;
    #pragma unroll
    for (int nf = 0; nf < 4; ++nf) {
      int d = 16 * nf + fr;
      float o = ov[nf][r] + rv[nf][r];
      u16 hh, ll;
      split_bf16(o, hh, ll);
      ohi[ob + d] = hh; olo[ob + d] = ll;
    }
  }
}

// ---------------------------------------------------------------------------
// Workspace (u16 units, ~135.7 MB):
//   qkvhi 24,207,360 | qkvlo 24,207,360 | xhi/xlo 2x8,069,120 (reused ohi/olo)
//   weffhi/lo 2x1,228,800 | wphi/lo 2x409,600 | tabKhi/lo 2x4,096
//   gM 7,168 | gMT 7,168
// ---------------------------------------------------------------------------
extern "C" void kernel_launch(void* const* d_in, const int* in_sizes, int n_in,
                              void* d_out, int out_size, void* d_ws, size_t ws_size,
                              hipStream_t stream) {
  (void)in_sizes; (void)n_in; (void)out_size; (void)ws_size;
  const float* x     = (const float*)d_in[0];
  const float* w_qkv = (const float*)d_in[1];
  const float* b_qkv = (const float*)d_in[2];
  const float* la    = (const float*)d_in[3];
  const float* lb    = (const float*)d_in[4];
  const float* tkv   = (const float*)d_in[5];
  const float* tkh   = (const float*)d_in[6];
  const float* tvv   = (const float*)d_in[7];
  const float* tvh   = (const float*)d_in[8];
  const float* wp    = (const float*)d_in[9];
  const float* b_p   = (const float*)d_in[10];

  u16* qkvhi  = (u16*)d_ws;
  u16* qkvlo  = qkvhi + (size_t)24207360;
  u16* xhi    = qkvlo + (size_t)24207360;
  u16* xlo    = xhi + (size_t)8069120;
  u16* ohi    = xhi;                       // alias (x splits dead after gemm1)
  u16* olo    = xlo;
  u16* weffhi = xlo + (size_t)8069120;
  u16* wefflo = weffhi + (size_t)1228800;
  u16* wphi   = wefflo + (size_t)1228800;
  u16* wplo   = wphi + (size_t)409600;
  u16* tabKhi = wplo + (size_t)409600;
  u16* tabKlo = tabKhi + (size_t)4096;
  u16* gM     = tabKlo + (size_t)4096;
  u16* gMT    = gM + (size_t)7168;

  // fused prep: x-split | weff | wproj | tables+gM+gMT (all concurrent)
  k_prep_all<<<14281, 256, 0, stream>>>(x, xhi, xlo,
                                        w_qkv, la, lb, weffhi, wefflo,
                                        wp, wphi, wplo,
                                        tkv, tkh, tabKhi, tabKlo, gM, gMT);

  // qkv = x @ weff^T + b_qkv -> split bf16 output (V tiles: 2-pass, hi-only)
  int nwg1 = ((MTOT + 127) / 128) * (C3 / 128);   // 99*15 = 1485
  k_gemm_mfma<1><<<nwg1, 512, 0, stream>>>(xhi, xlo, weffhi, wefflo, b_qkv,
                                           nullptr, qkvhi, qkvlo, MTOT, C3, C3 / 128, 10);

  // fused attention -> ohi/olo split (1-D grid, XCD-paired q-tiles)
  k_attn<<<BB * HH * 2, 512, 0, stream>>>(qkvhi, qkvlo, tabKhi, tabKlo, gM, gMT,
                                          tvv, tvh, ohi, olo);

  // out = o @ perm3(w_proj)^T + b_proj
  int nwg2 = ((MTOT + 127) / 128) * (CC / 128);   // 99*5 = 495
  k_gemm_mfma<0><<<nwg2, 512, 0, stream>>>(ohi, olo, wphi, wplo, b_p,
                                           (float*)d_out, nullptr, nullptr, MTOT, CC, CC / 128, 999);
}

// Round 21
// 262.674 us; speedup vs baseline: 1.0917x; 1.0030x over previous
//
#include <hip/hip_runtime.h>
#include <math.h>

#define BB 64
#define NN 197
#define HH 10
#define DD 64
#define CC 640
#define C3 1920
#define LR 64
#define MTOT (BB*NN)          // 12608
#define SCALE 0.125f

typedef unsigned short u16;
typedef unsigned long long u64;
typedef __bf16 bf16x8 __attribute__((ext_vector_type(8)));
typedef float f32x4 __attribute__((ext_vector_type(4)));

__device__ __forceinline__ void split_bf16(float f, u16& hi, u16& lo) {
  unsigned u = __float_as_uint(f);
  unsigned r = u + 0x7FFF + ((u >> 16) & 1);
  u16 hb = (u16)(r >> 16);
  float fh = __uint_as_float((unsigned)hb << 16);
  float dl = f - fh;
  unsigned u2 = __float_as_uint(dl);
  unsigned r2 = u2 + 0x7FFF + ((u2 >> 16) & 1);
  hi = hb; lo = (u16)(r2 >> 16);
}

__device__ __forceinline__ u16 bf16rn(float f) {
  unsigned u = __float_as_uint(f);
  return (u16)((u + 0x7FFF + ((u >> 16) & 1)) >> 16);
}
__device__ __forceinline__ float bf16tof(u16 v) {
  return __uint_as_float((unsigned)v << 16);
}

__device__ __forceinline__ int perm640(int i) {
  return (i < 214) ? 3 * i : (i < 427 ? 3 * (i - 214) + 1 : 3 * (i - 427) + 2);
}

// ---------------------------------------------------------------------------
// k_prep_all: fused independent prep (block-range dispatch, all concurrent):
//   [0, 7880):       x -> xhi/xlo split
//   [7880, 12680):   w_eff = perm3(w_qkv + (la@lb)^T) -> hi/lo
//   [12680, 14280):  w_proj perm640 -> hi/lo
//   14280:           tabK hi/lo + gM + gMT + gTvT (swizzle-linearized V-table
//                    transpose, staged by k_attn via glds)
// ---------------------------------------------------------------------------
__global__ __launch_bounds__(256) void k_prep_all(
    const float* __restrict__ x, u16* __restrict__ xhi, u16* __restrict__ xlo,
    const float* __restrict__ w_qkv, const float* __restrict__ la,
    const float* __restrict__ lb, u16* __restrict__ weffhi, u16* __restrict__ wefflo,
    const float* __restrict__ wp, u16* __restrict__ wphi, u16* __restrict__ wplo,
    const float* __restrict__ tkv, const float* __restrict__ tkh,
    const float* __restrict__ tvv, const float* __restrict__ tvh,
    u16* __restrict__ thi, u16* __restrict__ tlo,
    u16* __restrict__ gM, u16* __restrict__ gMT, u16* __restrict__ gTvT) {
  int bid = blockIdx.x;
  if (bid < 7880) {
    int i = bid * 256 + threadIdx.x;
    if (i >= (MTOT * CC) / 4) return;
    float4 v = ((const float4*)x)[i];
    float f[4] = {v.x, v.y, v.z, v.w};
    ushort4 H, L;
    u16 hh, ll;
    split_bf16(f[0], hh, ll); H.x = hh; L.x = ll;
    split_bf16(f[1], hh, ll); H.y = hh; L.y = ll;
    split_bf16(f[2], hh, ll); H.z = hh; L.z = ll;
    split_bf16(f[3], hh, ll); H.w = hh; L.w = ll;
    ((ushort4*)xhi)[i] = H;
    ((ushort4*)xlo)[i] = L;
  } else if (bid < 12680) {
    int idx = (bid - 7880) * 256 + threadIdx.x;   // covers 1920*640
    int i = idx / CC, j = idx % CC;
    int src = 3 * (i % CC) + (i / CC);
    float acc = w_qkv[(size_t)src * CC + j];
    const float* laj = la + (size_t)j * LR;
    const float* lbs = lb + src;
    #pragma unroll 8
    for (int r = 0; r < LR; ++r) acc = fmaf(laj[r], lbs[(size_t)r * C3], acc);
    u16 h, l; split_bf16(acc, h, l);
    weffhi[idx] = h; wefflo[idx] = l;
  } else if (bid < 14280) {
    int idx = (bid - 12680) * 256 + threadIdx.x;  // covers 640*640
    int i = idx / CC, j = idx % CC;
    float v = wp[(size_t)perm640(i) * CC + j];
    u16 h, l; split_bf16(v, h, l);
    wphi[idx] = h; wplo[idx] = l;
  } else {
    for (int idx = threadIdx.x; idx < 4096; idx += 256) {
      int row = idx >> 6, d = idx & 63;
      float v = row < 30 ? tkv[row * 64 + d] : (row < 60 ? tkh[(row - 30) * 64 + d] : 0.f);
      u16 hh, ll; split_bf16(v, hh, ll);
      thi[idx] = hh; tlo[idx] = ll;
    }
    for (int j = threadIdx.x; j < 7168; j += 256) {
      int b = 2 * j;
      u16 v = 0;
      int r0 = b / 448;
      for (int dr = -1; dr <= 1; ++dr) {
        int row = r0 + dr;
        if (row < 0 || row >= 32) continue;
        int g = (row & 7) ^ ((row >> 3) & 7);
        int off = (b ^ (g << 4)) - row * 448;
        if (off >= 0 && off < 448) {
          int k = off >> 1;
          if (k < 197) {
            int a1 = (k == 0) ? 14 : (k - 1) / 14;
            int a2 = (k == 0) ? 14 : (k - 1) % 14;
            if (row < 16) { if (row == a1) v = 0x3F80; }
            else          { if (row - 16 == a2) v = 0x3F80; }
          }
          break;
        }
      }
      gM[j] = v;
    }
    for (int j = threadIdx.x; j < 7168; j += 256) {
      int b = 2 * j;
      int row = b >> 6;
      int off = (b & 63) ^ (((row >> 1) & 3) << 4);
      int tcol = off >> 1;
      u16 v = 0;
      if (row < 197) {
        int a1 = (row == 0) ? 14 : (row - 1) / 14;
        int a2 = (row == 0) ? 14 : (row - 1) % 14;
        if (tcol < 16) { if (tcol == a1) v = 0x3F80; }
        else           { if (tcol - 16 == a2) v = 0x3F80; }
      }
      gMT[j] = v;
    }
    // gTvT: [64d][64tt] bf16 tile, swizzle-linearized
    // (tile byte = (d*64+tt)*2 ^ (g(d)<<4), g(d)=(d&7)^((d>>3)&7); row
    // stride 128B > XOR range so d = b>>7 unambiguous)
    for (int j = threadIdx.x; j < 4096; j += 256) {
      int b = 2 * j;
      int d = b >> 7;
      int g = (d & 7) ^ ((d >> 3) & 7);
      int off = (b ^ (g << 4)) & 127;
      int tt = off >> 1;
      float vv = 0.f;
      if (tt < 30) vv = tvv[tt * 64 + d];
      else if (tt >= 32 && tt < 62) vv = tvh[(tt - 32) * 64 + d];
      gTvT[j] = bf16rn(vv);
    }
  }
}

// ---------------------------------------------------------------------------
// Split-bf16 MFMA GEMM: 8 waves, 64x32 sub-tile/wave, LDS XOR-swizzle,
// n-inner 1D grid + bijective XCD remap. V-tiles (nt >= VNT): 2-pass, hi-only.
// ---------------------------------------------------------------------------
template<int OSPLIT>
__global__ __launch_bounds__(512, 4) void k_gemm_mfma(
    const u16* __restrict__ Ahi, const u16* __restrict__ Alo,
    const u16* __restrict__ Bhi, const u16* __restrict__ Blo,
    const float* __restrict__ bias, float* __restrict__ Cc,
    u16* __restrict__ Chi, u16* __restrict__ Clo,
    int M, int Nc, int NT, int VNT) {
  __shared__ u16 AsH[128][64];
  __shared__ u16 AsL[128][64];
  __shared__ u16 BsH[128][64];
  __shared__ u16 BsL[128][64];
  int t = threadIdx.x, w = t >> 6, l = t & 63;

  int nwg = gridDim.x, bid = blockIdx.x;
  int q8 = nwg >> 3, r8 = nwg & 7;
  int xcd = bid & 7, j8 = bid >> 3;
  int wgid = (xcd < r8 ? xcd * (q8 + 1) : r8 * (q8 + 1) + (xcd - r8) * q8) + j8;
  int mt = wgid / NT, nt = wgid - mt * NT;
  int m0 = mt * 128, n0 = nt * 128;
  bool vtile = (nt >= VNT);

  int wr = w & 1, wc = w >> 1;
  f32x4 acc[4][2] = {};
  int srow = l >> 3;
  int scol = ((l & 7) ^ srow) * 8;

  for (int k0 = 0; k0 < 640; k0 += 64) {
    for (int i = w; i < 16; i += 8) {
      int row = 8 * i + srow;
      int ga = m0 + row; if (ga >= M) ga = M - 1;
      size_t offA = (size_t)ga * 640 + k0 + scol;
      size_t offB = (size_t)(n0 + row) * 640 + k0 + scol;
      __builtin_amdgcn_global_load_lds(
          (const __attribute__((address_space(1))) void*)(Ahi + offA),
          (__attribute__((address_space(3))) void*)(&AsH[8 * i][0]), 16, 0, 0);
      __builtin_amdgcn_global_load_lds(
          (const __attribute__((address_space(1))) void*)(Alo + offA),
          (__attribute__((address_space(3))) void*)(&AsL[8 * i][0]), 16, 0, 0);
      __builtin_amdgcn_global_load_lds(
          (const __attribute__((address_space(1))) void*)(Bhi + offB),
          (__attribute__((address_space(3))) void*)(&BsH[8 * i][0]), 16, 0, 0);
      __builtin_amdgcn_global_load_lds(
          (const __attribute__((address_space(1))) void*)(Blo + offB),
          (__attribute__((address_space(3))) void*)(&BsL[8 * i][0]), 16, 0, 0);
    }
    __syncthreads();
    int fr = l & 15, fq = l >> 4;
    const unsigned char* pAH = (const unsigned char*)&AsH[0][0];
    const unsigned char* pAL = (const unsigned char*)&AsL[0][0];
    const unsigned char* pBH = (const unsigned char*)&BsH[0][0];
    const unsigned char* pBL = (const unsigned char*)&BsL[0][0];
    int fsw = (fr & 7) << 4;
    #pragma unroll
    for (int ks = 0; ks < 2; ++ks) {
      int cbyte = (ks * 64 + fq * 16) ^ fsw;
      bf16x8 ah[4], al[4], bh[2], bl[2];
      #pragma unroll
      for (int mi = 0; mi < 4; ++mi) {
        int ra = (wr * 64 + 16 * mi + fr) * 128 + cbyte;
        ah[mi] = *(const bf16x8*)(pAH + ra);
        al[mi] = *(const bf16x8*)(pAL + ra);
      }
      #pragma unroll
      for (int ni = 0; ni < 2; ++ni) {
        int rb = (wc * 32 + 16 * ni + fr) * 128 + cbyte;
        bh[ni] = *(const bf16x8*)(pBH + rb);
        bl[ni] = *(const bf16x8*)(pBL + rb);
      }
      #pragma unroll
      for (int mi = 0; mi < 4; ++mi)
        #pragma unroll
        for (int ni = 0; ni < 2; ++ni) {
          acc[mi][ni] = __builtin_amdgcn_mfma_f32_16x16x32_bf16(ah[mi], bh[ni], acc[mi][ni], 0, 0, 0);
          acc[mi][ni] = __builtin_amdgcn_mfma_f32_16x16x32_bf16(al[mi], bh[ni], acc[mi][ni], 0, 0, 0);
          if (!vtile)
            acc[mi][ni] = __builtin_amdgcn_mfma_f32_16x16x32_bf16(ah[mi], bl[ni], acc[mi][ni], 0, 0, 0);
        }
    }
    __syncthreads();
  }

  int fr = l & 15, fq = l >> 4;
  #pragma unroll
  for (int mi = 0; mi < 4; ++mi) {
    #pragma unroll
    for (int ni = 0; ni < 2; ++ni) {
      int col = n0 + wc * 32 + 16 * ni + fr;
      float bv = bias[col];
      #pragma unroll
      for (int r = 0; r < 4; ++r) {
        int row = m0 + wr * 64 + 16 * mi + fq * 4 + r;
        if (row < M) {
          float val = acc[mi][ni][r] + bv;
          if (OSPLIT) {
            u16 hh, ll; split_bf16(val, hh, ll);
            Chi[(size_t)row * Nc + col] = hh;
            if (!vtile) Clo[(size_t)row * Nc + col] = ll;
          } else {
            Cc[(size_t)row * Nc + col] = val;
          }
        }
      }
    }
  }
}

// ---------------------------------------------------------------------------
// Fused MFMA attention v9d: r20 structure; TvT table transpose moved to prep
// (gTvT, swizzle-linearized) and staged via ONE glds per wave — removes 8
// scalar fp32 loads + 8 scalar LDS writes per thread from the pre-B1 chain.
// Bit-identical values. 1-D 1280-block grid, inverse-XCD pair mapping (r20).
// ---------------------------------------------------------------------------
__global__ __launch_bounds__(512, 2) void k_attn(
    const u16* __restrict__ qkvhi, const u16* __restrict__ qkvlo,
    const u16* __restrict__ tabKhi, const u16* __restrict__ tabKlo,
    const u16* __restrict__ gM, const u16* __restrict__ gMT,
    const u16* __restrict__ gTvT,
    u16* __restrict__ ohi, u16* __restrict__ olo) {
  __shared__ __align__(16) unsigned char LDS[157696];
  unsigned char* Akhi = LDS;
  unsigned char* Aklo = LDS + 34816;
  unsigned char* VhM  = LDS + 69632;
  unsigned char* TvT  = LDS + 112640;
  unsigned char* PvB  = LDS + 120832;
  float* BvBh = (float*)(LDS + 120832);      // [128] stride 34 f32
  unsigned char* MTl  = LDS + 141312;        // [224][32] bf16 swz (S phase)
  unsigned char* Wb   = LDS + 141312;        // post-B2
  unsigned char* Pm   = LDS;

  // 1-D grid, inverse-XCD chunk map: (bh,qt) pair adjacent on same XCD
  int bid = blockIdx.x;
  int wgid = (bid & 7) * 160 + (bid >> 3);   // 1280 = 8 x 160, bijective
  int bh = wgid >> 1, qt = wgid & 1;
  int b = bh / HH, h = bh % HH;
  int t = threadIdx.x, w = t >> 6, l = t & 63;
  int fr = l & 15, fq = l >> 4;
  int q0 = 128 * qt;
  const size_t qbase = (size_t)(b * NN) * C3;

  int kr = l >> 3;
  int chunk = ((l & 7) ^ (kr & 7)) * 8;
  for (int i = w; i < 34; i += 8) {
    int rr = 8 * i + kr;
    const u16 *sh, *sl;
    if (rr < 208) {
      int kk = rr > 196 ? 196 : rr;
      sh = qkvhi + qbase + (size_t)kk * C3 + CC + h * DD + chunk;
      sl = qkvlo + qbase + (size_t)kk * C3 + CC + h * DD + chunk;
    } else {
      int tr = rr - 208;
      sh = tabKhi + tr * 64 + chunk;
      sl = tabKlo + tr * 64 + chunk;
    }
    __builtin_amdgcn_global_load_lds(
        (const __attribute__((address_space(1))) void*)sh,
        (__attribute__((address_space(3))) void*)(Akhi + i * 1024), 16, 0, 0);
    __builtin_amdgcn_global_load_lds(
        (const __attribute__((address_space(1))) void*)sl,
        (__attribute__((address_space(3))) void*)(Aklo + i * 1024), 16, 0, 0);
  }
  for (int i = w; i < 14; i += 8) {
    __builtin_amdgcn_global_load_lds(
        (const __attribute__((address_space(1))) void*)(gM + i * 512 + l * 8),
        (__attribute__((address_space(3))) void*)(VhM + 28672 + i * 1024), 16, 0, 0);
  }
  for (int i = w; i < 14; i += 8) {
    __builtin_amdgcn_global_load_lds(
        (const __attribute__((address_space(1))) void*)(gMT + i * 512 + l * 8),
        (__attribute__((address_space(3))) void*)(MTl + i * 1024), 16, 0, 0);
  }
  // TvT: one glds per wave (8 waves x 1024B = 8KB tile)
  __builtin_amdgcn_global_load_lds(
      (const __attribute__((address_space(1))) void*)(gTvT + w * 512 + l * 8),
      (__attribute__((address_space(3))) void*)(TvT + w * 1024), 16, 0, 0);
  // ---- V^T staging, k-quad batched: item = (kq 0..55, oct 0..7) ----
  if (t < 448) {
    int kq = t >> 3, d0v = (t & 7) * 8;
    int k0 = kq * 4;
    uint4 rowv[4];
    #pragma unroll
    for (int j = 0; j < 4; ++j) {
      int k = k0 + j;
      if (k < NN) {
        rowv[j] = *(const uint4*)(qkvhi + qbase + (size_t)k * C3 + 2 * CC + h * DD + d0v);
      } else {
        rowv[j] = make_uint4(0, 0, 0, 0);
      }
    }
    #pragma unroll
    for (int dd = 0; dd < 8; ++dd) {
      int word = dd >> 1, sh16 = (dd & 1) * 16;
      const unsigned* r0p = (const unsigned*)&rowv[0];
      const unsigned* r1p = (const unsigned*)&rowv[1];
      const unsigned* r2p = (const unsigned*)&rowv[2];
      const unsigned* r3p = (const unsigned*)&rowv[3];
      u64 e0 = (u16)(r0p[word] >> sh16);
      u64 e1 = (u16)(r1p[word] >> sh16);
      u64 e2 = (u16)(r2p[word] >> sh16);
      u64 e3 = (u16)(r3p[word] >> sh16);
      u64 pk = e0 | (e1 << 16) | (e2 << 32) | (e3 << 48);
      int d = d0v + dd;
      int byte = (d * 224 + k0) * 2; byte ^= (((d & 7) ^ ((d >> 3) & 7)) << 4);
      *(u64*)(VhM + byte) = pk;
    }
  }
  bool active = (q0 + 16 * w) < NN;
  bf16x8 qh[2], ql_[2];
  {
    int qg = q0 + 16 * w + fr; int qc = qg > 196 ? 196 : qg;
    const u16* qr  = qkvhi + qbase + (size_t)qc * C3 + h * DD;
    const u16* qr2 = qkvlo + qbase + (size_t)qc * C3 + h * DD;
    qh[0]  = *(const bf16x8*)(qr + 8 * fq);
    qh[1]  = *(const bf16x8*)(qr + 32 + 8 * fq);
    ql_[0] = *(const bf16x8*)(qr2 + 8 * fq);
    ql_[1] = *(const bf16x8*)(qr2 + 32 + 8 * fq);
  }
  __syncthreads();   // B1

  float ex[13][4];
  float inv[4];
  if (active) {
    f32x4 sacc[17] = {};
    #pragma unroll
    for (int ks = 0; ks < 2; ++ks)
      #pragma unroll
      for (int nf = 0; nf < 17; ++nf) {
        int row = 16 * nf + fr;
        int byte = row * 128 + 64 * ks + 16 * fq; byte ^= (row & 7) << 4;
        bf16x8 kf = *(const bf16x8*)(Akhi + byte);
        bf16x8 lf = *(const bf16x8*)(Aklo + byte);
        sacc[nf] = __builtin_amdgcn_mfma_f32_16x16x32_bf16(qh[ks],  kf, sacc[nf], 0, 0, 0);
        sacc[nf] = __builtin_amdgcn_mfma_f32_16x16x32_bf16(ql_[ks], kf, sacc[nf], 0, 0, 0);
        sacc[nf] = __builtin_amdgcn_mfma_f32_16x16x32_bf16(qh[ks],  lf, sacc[nf], 0, 0, 0);
      }
    #pragma unroll
    for (int nf = 13; nf < 17; ++nf)
      #pragma unroll
      for (int r = 0; r < 4; ++r) {
        int c = 16 * (nf - 13) + fr;
        if (c < 60) {
          int row = 16 * w + 4 * fq + r;
          *(u16*)(PvB + row * 160 + 2 * c) = bf16rn(sacc[nf][r]);
        }
      }
    bf16x8 psf;
    {
      int qrow = 16 * w + fr;
      int qg2 = q0 + qrow; int qc2 = qg2 > 196 ? 196 : qg2;
      const unsigned char* rowb = PvB + qrow * 160;
      u16 tmp[8];
      if (qc2 == 0) {
        u16 v0 = *(const u16*)(rowb);
        u16 h0 = *(const u16*)(rowb + 60);
        #pragma unroll
        for (int j = 0; j < 8; ++j) tmp[j] = (8 * fq + j < 16) ? v0 : h0;
      } else {
        int gq2 = (qc2 - 1) / 14, cq2 = (qc2 - 1) % 14;
        #pragma unroll
        for (int j = 0; j < 8; ++j) {
          int tt2 = 8 * fq + j;
          u16 v = 0;
          if (tt2 < 14)       v = *(const u16*)(rowb + 2 * (tt2 - gq2 + 15));
          else if (tt2 == 14) v = *(const u16*)(rowb);
          else if (tt2 >= 16 && tt2 < 30) v = *(const u16*)(rowb + 60 + 2 * (tt2 - 16 - cq2 + 15));
          else if (tt2 == 30) v = *(const u16*)(rowb + 60);
          tmp[j] = v;
        }
      }
      unsigned p0 = tmp[0] | ((unsigned)tmp[1] << 16);
      unsigned p1 = tmp[2] | ((unsigned)tmp[3] << 16);
      unsigned p2 = tmp[4] | ((unsigned)tmp[5] << 16);
      unsigned p3 = tmp[6] | ((unsigned)tmp[7] << 16);
      uint4 pk = make_uint4(p0, p1, p2, p3);
      psf = *(const bf16x8*)&pk;
    }
    #pragma unroll
    for (int nf = 0; nf < 13; ++nf) {
      int row = 16 * nf + fr;
      int byte = row * 64 + 16 * fq; byte ^= (((row >> 1) & 3) << 4);
      bf16x8 mtf = *(const bf16x8*)(MTl + byte);
      sacc[nf] = __builtin_amdgcn_mfma_f32_16x16x32_bf16(psf, mtf, sacc[nf], 0, 0, 0);
    }
    float mrow[4] = {-1e30f, -1e30f, -1e30f, -1e30f};
    #pragma unroll
    for (int nf = 0; nf < 13; ++nf) {
      int k = 16 * nf + fr;
      bool vk = k < 197;
      #pragma unroll
      for (int r = 0; r < 4; ++r) {
        float s = vk ? sacc[nf][r] * SCALE : -1e30f;
        ex[nf][r] = s;
        mrow[r] = fmaxf(mrow[r], s);
      }
    }
    #pragma unroll
    for (int r = 0; r < 4; ++r)
      #pragma unroll
      for (int mk = 1; mk < 16; mk <<= 1) mrow[r] = fmaxf(mrow[r], __shfl_xor(mrow[r], mk));
    float sum[4] = {0.f, 0.f, 0.f, 0.f};
    #pragma unroll
    for (int nf = 0; nf < 13; ++nf)
      #pragma unroll
      for (int r = 0; r < 4; ++r) {
        ex[nf][r] = __expf(ex[nf][r] - mrow[r]);
        sum[r] += ex[nf][r];
      }
    #pragma unroll
    for (int r = 0; r < 4; ++r) {
      #pragma unroll
      for (int mk = 1; mk < 16; mk <<= 1) sum[r] += __shfl_xor(sum[r], mk);
      inv[r] = 1.f / sum[r];
    }
  }
  __syncthreads();   // B2 (LAST barrier)

  #pragma unroll
  for (int nf = 0; nf < 14; ++nf)
    #pragma unroll
    for (int r = 0; r < 4; ++r) {
      int k = 16 * nf + fr;
      int row = 16 * w + 4 * fq + r;
      float p = 0.f;
      if (active && nf < 13 && k < 197) p = ex[nf][r] * inv[r];
      int byte = row * 448 + 2 * k; byte ^= (((row & 7) ^ ((row >> 3) & 7)) << 4);
      *(u16*)(Pm + byte) = bf16rn(p);
    }

  int prow = 16 * w + fr;
  int pswz = ((prow & 7) ^ ((prow >> 3) & 7)) << 4;
  f32x4 ov[4] = {};
  f32x4 om[2] = {};
  #pragma unroll
  for (int ks = 0; ks < 7; ++ks) {
    int co = 64 * ks + 16 * fq;
    bf16x8 pah = *(const bf16x8*)(Pm + ((prow * 448 + co) ^ pswz));
    #pragma unroll
    for (int nf = 0; nf < 4; ++nf) {
      int vrow = 16 * nf + fr;
      int vswz = ((vrow & 7) ^ ((vrow >> 3) & 7)) << 4;
      bf16x8 v = *(const bf16x8*)(VhM + ((vrow * 448 + co) ^ vswz));
      ov[nf] = __builtin_amdgcn_mfma_f32_16x16x32_bf16(pah, v, ov[nf], 0, 0, 0);
    }
    #pragma unroll
    for (int mf = 0; mf < 2; ++mf) {
      int mr = 64 + 16 * mf + fr;
      int mswz = ((mr & 7) ^ ((mr >> 3) & 7)) << 4;
      bf16x8 mv = *(const bf16x8*)(VhM + ((mr * 448 + co) ^ mswz));
      om[mf] = __builtin_amdgcn_mfma_f32_16x16x32_bf16(pah, mv, om[mf], 0, 0, 0);
    }
  }
  #pragma unroll
  for (int mf = 0; mf < 2; ++mf)
    #pragma unroll
    for (int r = 0; r < 4; ++r)
      BvBh[(16 * w + 4 * fq + r) * 34 + 16 * mf + fr] = om[mf][r];

  {
    int row = 16 * w + (l >> 2);
    int qg = q0 + row;
    int half = (l & 3) >> 1;
    int u0 = (l & 1) * 16;
    const float* bb = &BvBh[row * 34 + 16 * half];
    u16 wv[16];
    if (qg == 0) {
      float s = 0.f;
      #pragma unroll
      for (int a = 0; a < 15; ++a) s += bb[a];
      u16 sv = bf16rn(s);
      #pragma unroll
      for (int j = 0; j < 16; ++j) wv[j] = (u0 + j == 0) ? sv : (u16)0;
    } else if (qg < NN) {
      int m = qg - 1;
      int sel = half ? (m % 14) : (m / 14);
      #pragma unroll
      for (int j = 0; j < 16; ++j) {
        int u = u0 + j;
        float val;
        if (u == 0) val = bb[14];
        else {
          int a = u - 15 + sel;
          val = (a >= 0 && a < 14) ? bb[a] : 0.f;
        }
        wv[j] = bf16rn(val);
      }
    } else {
      #pragma unroll
      for (int j = 0; j < 16; ++j) wv[j] = 0;
    }
    uint4 p0, p1;
    p0.x = wv[0]  | ((unsigned)wv[1]  << 16);
    p0.y = wv[2]  | ((unsigned)wv[3]  << 16);
    p0.z = wv[4]  | ((unsigned)wv[5]  << 16);
    p0.w = wv[6]  | ((unsigned)wv[7]  << 16);
    p1.x = wv[8]  | ((unsigned)wv[9]  << 16);
    p1.y = wv[10] | ((unsigned)wv[11] << 16);
    p1.z = wv[12] | ((unsigned)wv[13] << 16);
    p1.w = wv[14] | ((unsigned)wv[15] << 16);
    int base = row * 128 + (l & 3) * 32;
    int sz = ((row & 7) ^ ((row >> 3) & 7)) << 4;
    *(uint4*)(Wb + (base ^ sz)) = p0;
    *(uint4*)(Wb + ((base + 16) ^ sz)) = p1;
  }

  f32x4 rv[4] = {};
  #pragma unroll
  for (int ks2 = 0; ks2 < 2; ++ks2) {
    int co = 64 * ks2 + 16 * fq;
    bf16x8 wa = *(const bf16x8*)(Wb + ((prow * 128 + co) ^ pswz));
    #pragma unroll
    for (int nf = 0; nf < 4; ++nf) {
      int vrow = 16 * nf + fr;
      int vswz = ((vrow & 7) ^ ((vrow >> 3) & 7)) << 4;
      bf16x8 tv = *(const bf16x8*)(TvT + ((vrow * 128 + co) ^ vswz));
      rv[nf] = __builtin_amdgcn_mfma_f32_16x16x32_bf16(wa, tv, rv[nf], 0, 0, 0);
    }
  }

  #pragma unroll
  for (int r = 0; r < 4; ++r) {
    int qrl = 16 * w + 4 * fq + r;
    int qg = q0 + qrl;
    if (qg >= NN) continue;
    size_t ob = (size_t)(b * NN + qg) * CC + h * DD;
    #pragma unroll
    for (int nf = 0; nf < 4; ++nf) {
      int d = 16 * nf + fr;
      float o = ov[nf][r] + rv[nf][r];
      u16 hh, ll;
      split_bf16(o, hh, ll);
      ohi[ob + d] = hh; olo[ob + d] = ll;
    }
  }
}

// ---------------------------------------------------------------------------
// Workspace (u16 units, ~135.7 MB):
//   qkvhi 24,207,360 | qkvlo 24,207,360 | xhi/xlo 2x8,069,120 (reused ohi/olo)
//   weffhi/lo 2x1,228,800 | wphi/lo 2x409,600 | tabKhi/lo 2x4,096
//   gM 7,168 | gMT 7,168 | gTvT 4,096
// ---------------------------------------------------------------------------
extern "C" void kernel_launch(void* const* d_in, const int* in_sizes, int n_in,
                              void* d_out, int out_size, void* d_ws, size_t ws_size,
                              hipStream_t stream) {
  (void)in_sizes; (void)n_in; (void)out_size; (void)ws_size;
  const float* x     = (const float*)d_in[0];
  const float* w_qkv = (const float*)d_in[1];
  const float* b_qkv = (const float*)d_in[2];
  const float* la    = (const float*)d_in[3];
  const float* lb    = (const float*)d_in[4];
  const float* tkv   = (const float*)d_in[5];
  const float* tkh   = (const float*)d_in[6];
  const float* tvv   = (const float*)d_in[7];
  const float* tvh   = (const float*)d_in[8];
  const float* wp    = (const float*)d_in[9];
  const float* b_p   = (const float*)d_in[10];

  u16* qkvhi  = (u16*)d_ws;
  u16* qkvlo  = qkvhi + (size_t)24207360;
  u16* xhi    = qkvlo + (size_t)24207360;
  u16* xlo    = xhi + (size_t)8069120;
  u16* ohi    = xhi;                       // alias (x splits dead after gemm1)
  u16* olo    = xlo;
  u16* weffhi = xlo + (size_t)8069120;
  u16* wefflo = weffhi + (size_t)1228800;
  u16* wphi   = wefflo + (size_t)1228800;
  u16* wplo   = wphi + (size_t)409600;
  u16* tabKhi = wplo + (size_t)409600;
  u16* tabKlo = tabKhi + (size_t)4096;
  u16* gM     = tabKlo + (size_t)4096;
  u16* gMT    = gM + (size_t)7168;
  u16* gTvT   = gMT + (size_t)7168;

  // fused prep: x-split | weff | wproj | tables+gM+gMT+gTvT (all concurrent)
  k_prep_all<<<14281, 256, 0, stream>>>(x, xhi, xlo,
                                        w_qkv, la, lb, weffhi, wefflo,
                                        wp, wphi, wplo,
                                        tkv, tkh, tvv, tvh, tabKhi, tabKlo,
                                        gM, gMT, gTvT);

  // qkv = x @ weff^T + b_qkv -> split bf16 output (V tiles: 2-pass, hi-only)
  int nwg1 = ((MTOT + 127) / 128) * (C3 / 128);   // 99*15 = 1485
  k_gemm_mfma<1><<<nwg1, 512, 0, stream>>>(xhi, xlo, weffhi, wefflo, b_qkv,
                                           nullptr, qkvhi, qkvlo, MTOT, C3, C3 / 128, 10);

  // fused attention -> ohi/olo split (1-D grid, XCD-paired q-tiles)
  k_attn<<<BB * HH * 2, 512, 0, stream>>>(qkvhi, qkvlo, tabKhi, tabKlo, gM, gMT,
                                          gTvT, ohi, olo);

  // out = o @ perm3(w_proj)^T + b_proj
  int nwg2 = ((MTOT + 127) / 128) * (CC / 128);   // 99*5 = 495
  k_gemm_mfma<0><<<nwg2, 512, 0, stream>>>(ohi, olo, wphi, wplo, b_p,
                                           (float*)d_out, nullptr, nullptr, MTOT, CC, CC / 128, 999);
}